// Round 2
// baseline (226.298 us; speedup 1.0000x reference)
//
#include <hip/hip_runtime.h>

typedef __attribute__((ext_vector_type(8))) short short8;
typedef __attribute__((ext_vector_type(4))) float f32x4;

#define N_ 2048

__device__ __forceinline__ unsigned short f2bf(float f) {
  unsigned int x = __builtin_bit_cast(unsigned int, f);
  x += 0x7fffu + ((x >> 16) & 1u);
  return (unsigned short)(x >> 16);
}

// ---------------- Kernel 1: fr = h @ Wr ; sr = sum(leaky(fr)*ar) ; frB bf16 ----------------
// grid (64, 8) block 256. col-tile = one head (64 hd cols).
__global__ __launch_bounds__(256) void k_proj_fr(
    const float* __restrict__ h, const float* __restrict__ Wr,
    const float* __restrict__ ar,
    unsigned short* __restrict__ frB, float* __restrict__ sr)
{
  __shared__ float As[32][68];   // [k][m]
  __shared__ float Bs[32][68];   // [k][o]
  __shared__ float sred[64][17];
  const int tid = threadIdx.x;
  const int tx = tid & 15, ty = tid >> 4;
  const int rowbase = blockIdx.x * 64;
  const int hh = blockIdx.y;
  const int colbase = hh * 64;

  float acc[4][4];
#pragma unroll
  for (int i = 0; i < 4; ++i)
#pragma unroll
    for (int j = 0; j < 4; ++j) acc[i][j] = 0.f;

  const int ar_ = tid >> 3;        // 0..31
  const int ak4 = (tid & 7) * 4;   // 0..28
  const int bk  = tid >> 4;        // 0..15
  const int bc4 = tx * 4;

  for (int kt = 0; kt < 512; kt += 32) {
    f32x4 a0 = *reinterpret_cast<const f32x4*>(&h[(rowbase + ar_) * 512 + kt + ak4]);
    f32x4 a1 = *reinterpret_cast<const f32x4*>(&h[(rowbase + ar_ + 32) * 512 + kt + ak4]);
    f32x4 b0 = *reinterpret_cast<const f32x4*>(&Wr[(kt + bk) * 512 + colbase + bc4]);
    f32x4 b1 = *reinterpret_cast<const f32x4*>(&Wr[(kt + bk + 16) * 512 + colbase + bc4]);
    __syncthreads();
#pragma unroll
    for (int i = 0; i < 4; ++i) { As[ak4 + i][ar_] = a0[i]; As[ak4 + i][ar_ + 32] = a1[i]; }
    *reinterpret_cast<f32x4*>(&Bs[bk][bc4]) = b0;
    *reinterpret_cast<f32x4*>(&Bs[bk + 16][bc4]) = b1;
    __syncthreads();
#pragma unroll
    for (int kk = 0; kk < 32; ++kk) {
      f32x4 a = *reinterpret_cast<const f32x4*>(&As[kk][ty * 4]);
      f32x4 b = *reinterpret_cast<const f32x4*>(&Bs[kk][tx * 4]);
#pragma unroll
      for (int i = 0; i < 4; ++i)
#pragma unroll
        for (int j = 0; j < 4; ++j) acc[i][j] += a[i] * b[j];
    }
  }

  const int b = rowbase >> 11;
  const int bh = b * 8 + hh;
  f32x4 arv = *reinterpret_cast<const f32x4*>(&ar[tx * 4]);
#pragma unroll
  for (int i = 0; i < 4; ++i) {
    float ps = 0.f;
#pragma unroll
    for (int j = 0; j < 4; ++j) {
      float v = acc[i][j];
      float lv = v >= 0.f ? v : 0.01f * v;
      ps += lv * arv[j];
    }
    sred[ty * 4 + i][tx] = ps;
  }
  __syncthreads();
  if (tid < 64) {
    float s = 0.f;
#pragma unroll
    for (int t = 0; t < 16; ++t) s += sred[tid][t];
    sr[bh * N_ + (rowbase & 2047) + tid] = s;
  }
  // frB layout: [bh][n>>3][hd][n&7] bf16 (PV B-fragment friendly)
#pragma unroll
  for (int i = 0; i < 4; ++i) {
    int n = (rowbase & 2047) + ty * 4 + i;
    int nb = n >> 3, e = n & 7;
#pragma unroll
    for (int j = 0; j < 4; ++j) {
      int hd = tx * 4 + j;
      frB[((bh * 256 + nb) * 64 + hd) * 8 + e] = f2bf(acc[i][j]);
    }
  }
}

// ---------------- Kernel 2: rk = rh @ Wrs, rq = rh @ Wrt (bf16, [bh][n][16]) ----------------
// grid (2048) block 256: 2 rows x 128 cols per block
__global__ __launch_bounds__(256) void k_projr(
    const float* __restrict__ rh, const float* __restrict__ Wrs,
    const float* __restrict__ Wrt,
    unsigned short* __restrict__ rk, unsigned short* __restrict__ rq)
{
  const int tid = threadIdx.x;
  const int col = tid & 127;      // h*16 + r
  const int ro  = tid >> 7;       // 0..1
  const int nf  = blockIdx.x * 2 + ro;  // flat b*N+n
  const f32x4* src = reinterpret_cast<const f32x4*>(&rh[nf * 16]);
  f32x4 rv[4] = {src[0], src[1], src[2], src[3]};
  float sk = 0.f, sq = 0.f;
#pragma unroll
  for (int k4 = 0; k4 < 4; ++k4)
#pragma unroll
    for (int j = 0; j < 4; ++j) {
      float v = rv[k4][j];
      int k = k4 * 4 + j;
      sk += v * Wrs[k * 128 + col];
      sq += v * Wrt[k * 128 + col];
    }
  int bb = nf >> 11, n = nf & 2047, hh = col >> 4, r = col & 15;
  int oidx = ((bb * 8 + hh) * N_ + n) * 16 + r;
  rk[oidx] = f2bf(sk);
  rq[oidx] = f2bf(sq);
}

// ---------------- Kernel 3: flash attention (MFMA) ----------------
// grid (32, 16) block 256 = 4 waves; each wave owns 16 query rows, no barriers.
__global__ __launch_bounds__(256) void k_attn(
    const unsigned short* __restrict__ rk,   // [bh][n][16] bf16
    const unsigned short* __restrict__ rq,   // [bh][n][16] bf16
    const float* __restrict__ sr,            // [bh][n]
    const unsigned short* __restrict__ frB,  // [bh][n>>3][hd][n&7] bf16
    float* __restrict__ ctx)                 // [b*N+n][512]
{
  __shared__ unsigned short P_lds[4][16][72];
  const int tid = threadIdx.x;
  const int wave = tid >> 6, lane = tid & 63;
  const int c = lane & 15, g = lane >> 4;
  const int bh = blockIdx.y;
  const int b = bh >> 3, hh = bh & 7;
  const int qbase = blockIdx.x * 64 + wave * 16;

  // A-fragment: rk rows (K=16 zero-padded to 32: groups g>=2 hold zeros)
  short8 a_rk = {0, 0, 0, 0, 0, 0, 0, 0};
  if (g < 2)
    a_rk = *reinterpret_cast<const short8*>(&rk[(bh * N_ + qbase + c) * 16 + 8 * g]);

  f32x4 O[4];
#pragma unroll
  for (int t = 0; t < 4; ++t) O[t] = (f32x4){0.f, 0.f, 0.f, 0.f};
  float m[4], l[4];
#pragma unroll
  for (int r = 0; r < 4; ++r) { m[r] = -1e30f; l[r] = 0.f; }

  for (int j0 = 0; j0 < N_; j0 += 64) {
    // ---- scores: S[i][j] = rk[i]·rq[j] + sr[j]
    f32x4 S[4];
#pragma unroll
    for (int jt = 0; jt < 4; ++jt) {
      short8 b_rq = {0, 0, 0, 0, 0, 0, 0, 0};
      if (g < 2)
        b_rq = *reinterpret_cast<const short8*>(&rq[(bh * N_ + j0 + jt * 16 + c) * 16 + 8 * g]);
      f32x4 z = {0.f, 0.f, 0.f, 0.f};
      S[jt] = __builtin_amdgcn_mfma_f32_16x16x32_bf16(a_rk, b_rq, z, 0, 0, 0);
      float srv = sr[bh * N_ + j0 + jt * 16 + c];
      S[jt][0] += srv; S[jt][1] += srv; S[jt][2] += srv; S[jt][3] += srv;
    }
    // ---- online softmax per row (row i = 4g+r, cols across lanes c and jt)
    float scal[4];
#pragma unroll
    for (int r = 0; r < 4; ++r) {
      float tmax = fmaxf(fmaxf(S[0][r], S[1][r]), fmaxf(S[2][r], S[3][r]));
      tmax = fmaxf(tmax, __shfl_xor(tmax, 1));
      tmax = fmaxf(tmax, __shfl_xor(tmax, 2));
      tmax = fmaxf(tmax, __shfl_xor(tmax, 4));
      tmax = fmaxf(tmax, __shfl_xor(tmax, 8));
      float mn = fmaxf(m[r], tmax);
      float sc = __expf(m[r] - mn);
      float ps = 0.f;
#pragma unroll
      for (int jt = 0; jt < 4; ++jt) {
        float pv = __expf(S[jt][r] - mn);
        S[jt][r] = pv;
        ps += pv;
      }
      ps += __shfl_xor(ps, 1);
      ps += __shfl_xor(ps, 2);
      ps += __shfl_xor(ps, 4);
      ps += __shfl_xor(ps, 8);
      l[r] = l[r] * sc + ps;
      m[r] = mn;
      scal[r] = sc;
    }
#pragma unroll
    for (int ht = 0; ht < 4; ++ht)
#pragma unroll
      for (int r = 0; r < 4; ++r) O[ht][r] *= scal[r];
    // ---- P (C/D layout) -> LDS -> A-fragment layout (wave-private, no barrier)
#pragma unroll
    for (int jt = 0; jt < 4; ++jt)
#pragma unroll
      for (int r = 0; r < 4; ++r)
        P_lds[wave][4 * g + r][jt * 16 + c] = f2bf(S[jt][r]);
    // ---- PV: O[16 x 64] += P[16 x 64] @ fr[64 x 64]
#pragma unroll
    for (int kk = 0; kk < 2; ++kk) {
      short8 pa = *reinterpret_cast<const short8*>(&P_lds[wave][c][kk * 32 + 8 * g]);
      int nb = (j0 >> 3) + kk * 4 + g;
#pragma unroll
      for (int ht = 0; ht < 4; ++ht) {
        short8 bv = *reinterpret_cast<const short8*>(
            &frB[((bh * 256 + nb) * 64 + ht * 16 + c) * 8]);
        O[ht] = __builtin_amdgcn_mfma_f32_16x16x32_bf16(pa, bv, O[ht], 0, 0, 0);
      }
    }
  }
  // ---- epilogue: ctx[b][n][h*64+hd] = O / l
#pragma unroll
  for (int ht = 0; ht < 4; ++ht)
#pragma unroll
    for (int r = 0; r < 4; ++r) {
      int n = qbase + 4 * g + r;
      ctx[(b * N_ + n) * 512 + hh * 64 + ht * 16 + c] = O[ht][r] / l[r];
    }
}

// ---------------- Kernel 4: x = ctx @ Wf + h ----------------
__global__ __launch_bounds__(256) void k_final(
    const float* __restrict__ ctx, const float* __restrict__ Wf,
    const float* __restrict__ h, float* __restrict__ x)
{
  __shared__ float As[32][68];
  __shared__ float Bs[32][68];
  const int tid = threadIdx.x;
  const int tx = tid & 15, ty = tid >> 4;
  const int rowbase = blockIdx.x * 64;
  const int colbase = blockIdx.y * 64;

  float acc[4][4];
#pragma unroll
  for (int i = 0; i < 4; ++i)
#pragma unroll
    for (int j = 0; j < 4; ++j) acc[i][j] = 0.f;

  const int ar_ = tid >> 3;
  const int ak4 = (tid & 7) * 4;
  const int bk  = tid >> 4;
  const int bc4 = tx * 4;

  for (int kt = 0; kt < 512; kt += 32) {
    f32x4 a0 = *reinterpret_cast<const f32x4*>(&ctx[(rowbase + ar_) * 512 + kt + ak4]);
    f32x4 a1 = *reinterpret_cast<const f32x4*>(&ctx[(rowbase + ar_ + 32) * 512 + kt + ak4]);
    f32x4 b0 = *reinterpret_cast<const f32x4*>(&Wf[(kt + bk) * 512 + colbase + bc4]);
    f32x4 b1 = *reinterpret_cast<const f32x4*>(&Wf[(kt + bk + 16) * 512 + colbase + bc4]);
    __syncthreads();
#pragma unroll
    for (int i = 0; i < 4; ++i) { As[ak4 + i][ar_] = a0[i]; As[ak4 + i][ar_ + 32] = a1[i]; }
    *reinterpret_cast<f32x4*>(&Bs[bk][bc4]) = b0;
    *reinterpret_cast<f32x4*>(&Bs[bk + 16][bc4]) = b1;
    __syncthreads();
#pragma unroll
    for (int kk = 0; kk < 32; ++kk) {
      f32x4 a = *reinterpret_cast<const f32x4*>(&As[kk][ty * 4]);
      f32x4 b = *reinterpret_cast<const f32x4*>(&Bs[kk][tx * 4]);
#pragma unroll
      for (int i = 0; i < 4; ++i)
#pragma unroll
        for (int j = 0; j < 4; ++j) acc[i][j] += a[i] * b[j];
    }
  }
#pragma unroll
  for (int i = 0; i < 4; ++i) {
    int row = rowbase + ty * 4 + i;
    f32x4 hv = *reinterpret_cast<const f32x4*>(&h[row * 512 + colbase + tx * 4]);
    f32x4 o;
#pragma unroll
    for (int j = 0; j < 4; ++j) o[j] = acc[i][j] + hv[j];
    *reinterpret_cast<f32x4*>(&x[row * 512 + colbase + tx * 4]) = o;
  }
}

// ---------------- Kernel 5: LayerNorm ----------------
// grid (1024) block 256: one wave per row
__global__ __launch_bounds__(256) void k_ln(
    const float* __restrict__ x, const float* __restrict__ gamma,
    const float* __restrict__ beta, float* __restrict__ out)
{
  const int lane = threadIdx.x & 63;
  const int row = blockIdx.x * 4 + (threadIdx.x >> 6);
  const f32x4* xr = reinterpret_cast<const f32x4*>(&x[row * 512]);
  f32x4 v0 = xr[lane * 2], v1 = xr[lane * 2 + 1];
  float s = 0.f, sq = 0.f;
#pragma unroll
  for (int j = 0; j < 4; ++j) {
    s += v0[j] + v1[j];
    sq += v0[j] * v0[j] + v1[j] * v1[j];
  }
#pragma unroll
  for (int msk = 1; msk < 64; msk <<= 1) {
    s += __shfl_xor(s, msk);
    sq += __shfl_xor(sq, msk);
  }
  float mu = s * (1.f / 512.f);
  float var = sq * (1.f / 512.f) - mu * mu;
  float rs = rsqrtf(var + 1e-5f);
  const f32x4* gr = reinterpret_cast<const f32x4*>(&gamma[lane * 8]);
  const f32x4* br = reinterpret_cast<const f32x4*>(&beta[lane * 8]);
  f32x4 g0 = gr[0], g1 = gr[1], b0 = br[0], b1 = br[1];
  f32x4 o0, o1;
#pragma unroll
  for (int j = 0; j < 4; ++j) {
    o0[j] = (v0[j] - mu) * rs * g0[j] + b0[j];
    o1[j] = (v1[j] - mu) * rs * g1[j] + b1[j];
  }
  f32x4* orow = reinterpret_cast<f32x4*>(&out[row * 512]);
  orow[lane * 2] = o0;
  orow[lane * 2 + 1] = o1;
}

extern "C" void kernel_launch(void* const* d_in, const int* in_sizes, int n_in,
                              void* d_out, int out_size, void* d_ws, size_t ws_size,
                              hipStream_t stream) {
  const float* h     = (const float*)d_in[0];
  const float* rh    = (const float*)d_in[1];
  // d_in[2] = Wl, d_in[4] = al: dead (softmax shift-invariance along j)
  const float* Wr    = (const float*)d_in[3];
  const float* ar    = (const float*)d_in[5];
  const float* Wrs   = (const float*)d_in[6];
  const float* Wrt   = (const float*)d_in[7];
  const float* Wf    = (const float*)d_in[8];
  const float* gamma = (const float*)d_in[9];
  const float* beta  = (const float*)d_in[10];

  char* ws = (char*)d_ws;
  unsigned short* frB = (unsigned short*)(ws);                         // 4 MB
  unsigned short* rk  = (unsigned short*)(ws + 4 * 1024 * 1024);       // 1 MB
  unsigned short* rq  = (unsigned short*)(ws + 5 * 1024 * 1024);       // 1 MB
  float* sr  = (float*)(ws + 6 * 1024 * 1024);                         // 128 KB
  float* ctx = (float*)(ws + 6 * 1024 * 1024 + 256 * 1024);            // 8 MB
  float* x   = (float*)(ws + 14 * 1024 * 1024 + 256 * 1024);           // 8 MB
  float* out = (float*)d_out;

  hipLaunchKernelGGL(k_proj_fr, dim3(64, 8), dim3(256), 0, stream, h, Wr, ar, frB, sr);
  hipLaunchKernelGGL(k_projr, dim3(2048), dim3(256), 0, stream, rh, Wrs, Wrt, rk, rq);
  hipLaunchKernelGGL(k_attn, dim3(32, 16), dim3(256), 0, stream, rk, rq, sr, frB, ctx);
  hipLaunchKernelGGL(k_final, dim3(64, 8), dim3(256), 0, stream, ctx, Wf, h, x);
  hipLaunchKernelGGL(k_ln, dim3(1024), dim3(256), 0, stream, x, gamma, beta, out);
}

// Round 3
// 198.036 us; speedup vs baseline: 1.1427x; 1.1427x over previous
//
#include <hip/hip_runtime.h>

typedef __attribute__((ext_vector_type(8))) short short8;
typedef __attribute__((ext_vector_type(4))) float f32x4;
typedef __attribute__((ext_vector_type(4))) unsigned int u32x4;
typedef __attribute__((ext_vector_type(2))) unsigned int u32x2;

#define N_ 2048

__device__ __forceinline__ unsigned short f2bf(float f) {
  unsigned int x = __builtin_bit_cast(unsigned int, f);
  x += 0x7fffu + ((x >> 16) & 1u);
  return (unsigned short)(x >> 16);
}
__device__ __forceinline__ float bf2f(unsigned short u) {
  return __builtin_bit_cast(float, ((unsigned int)u) << 16);
}
__device__ __forceinline__ unsigned int pack2(float lo, float hi) {
  return ((unsigned int)f2bf(hi) << 16) | (unsigned int)f2bf(lo);
}

// ---------------- cast h -> bf16 ----------------
__global__ __launch_bounds__(256) void k_cast_h(const float* __restrict__ h,
                                                unsigned short* __restrict__ hB) {
  int idx = (blockIdx.x * 256 + threadIdx.x) * 8;
  f32x4 v0 = *reinterpret_cast<const f32x4*>(&h[idx]);
  f32x4 v1 = *reinterpret_cast<const f32x4*>(&h[idx + 4]);
  u32x4 pw;
  pw[0] = pack2(v0[0], v0[1]);
  pw[1] = pack2(v0[2], v0[3]);
  pw[2] = pack2(v1[0], v1[1]);
  pw[3] = pack2(v1[2], v1[3]);
  *reinterpret_cast<u32x4*>(&hB[idx]) = pw;
}

// ---------------- transpose-cast Wr, Wf -> WrT, WfT (bf16 [col][k]) ----------------
__global__ __launch_bounds__(256) void k_cast_wT(const float* __restrict__ Wr,
                                                 const float* __restrict__ Wf,
                                                 unsigned short* __restrict__ WrT,
                                                 unsigned short* __restrict__ WfT) {
  const float* W = blockIdx.z ? Wf : Wr;
  unsigned short* WT = blockIdx.z ? WfT : WrT;
  __shared__ float t[32][33];
  const int kt = blockIdx.x * 32, ct = blockIdx.y * 32;
  const int r = threadIdx.x >> 3, c4 = (threadIdx.x & 7) * 4;
  f32x4 v = *reinterpret_cast<const f32x4*>(&W[(kt + r) * 512 + ct + c4]);
#pragma unroll
  for (int j = 0; j < 4; ++j) t[r][c4 + j] = v[j];
  __syncthreads();
  u32x2 o;
  o[0] = pack2(t[c4][r], t[c4 + 1][r]);
  o[1] = pack2(t[c4 + 2][r], t[c4 + 3][r]);
  *reinterpret_cast<u32x2*>(&WT[(ct + r) * 512 + kt + c4]) = o;
}

// ---------------- rk = rh @ Wrs, rq = rh @ Wrt (bf16, [bh][n][16]) ----------------
__global__ __launch_bounds__(256) void k_projr(
    const float* __restrict__ rh, const float* __restrict__ Wrs,
    const float* __restrict__ Wrt,
    unsigned short* __restrict__ rk, unsigned short* __restrict__ rq) {
  const int tid = threadIdx.x;
  const int col = tid & 127;
  const int ro = tid >> 7;
  const int nf = blockIdx.x * 2 + ro;
  const f32x4* src = reinterpret_cast<const f32x4*>(&rh[nf * 16]);
  f32x4 rv[4] = {src[0], src[1], src[2], src[3]};
  float sk = 0.f, sq = 0.f;
#pragma unroll
  for (int k4 = 0; k4 < 4; ++k4)
#pragma unroll
    for (int j = 0; j < 4; ++j) {
      float v = rv[k4][j];
      int k = k4 * 4 + j;
      sk += v * Wrs[k * 128 + col];
      sq += v * Wrt[k * 128 + col];
    }
  int bb = nf >> 11, n = nf & 2047, hh = col >> 4, r = col & 15;
  int oidx = ((bb * 8 + hh) * N_ + n) * 16 + r;
  rk[oidx] = f2bf(sk);
  rq[oidx] = f2bf(sq);
}

// ---------------- fr = hB @ WrT (MFMA); sr; frB (k-permuted PV layout) ----------------
// grid 256 blocks of 16 rows; 8 waves, wave w = head w (64 cols).
__global__ __launch_bounds__(512) void k_proj_fr(
    const unsigned short* __restrict__ hB, const unsigned short* __restrict__ WrT,
    const float* __restrict__ ar,
    unsigned short* __restrict__ frB, float* __restrict__ sr) {
  const int tid = threadIdx.x;
  const int w = tid >> 6, lane = tid & 63;
  const int c = lane & 15, g = lane >> 4;
  const int rowbase = blockIdx.x * 16;

  f32x4 acc[4];
#pragma unroll
  for (int i = 0; i < 4; ++i) acc[i] = (f32x4){0.f, 0.f, 0.f, 0.f};

#pragma unroll 4
  for (int kt = 0; kt < 512; kt += 32) {
    short8 a = *reinterpret_cast<const short8*>(&hB[(rowbase + c) * 512 + kt + 8 * g]);
#pragma unroll
    for (int ht = 0; ht < 4; ++ht) {
      short8 bv = *reinterpret_cast<const short8*>(
          &WrT[(w * 64 + ht * 16 + c) * 512 + kt + 8 * g]);
      acc[ht] = __builtin_amdgcn_mfma_f32_16x16x32_bf16(a, bv, acc[ht], 0, 0, 0);
    }
  }

  const int b = rowbase >> 11;
  const int bh = b * 8 + w;
  const int nloc = rowbase & 2047;
  const int jb = nloc >> 5;
  const int t = (nloc >> 4) & 1;

  float arv[4];
#pragma unroll
  for (int ht = 0; ht < 4; ++ht) arv[ht] = ar[ht * 16 + c];

  float ps[4];
#pragma unroll
  for (int r = 0; r < 4; ++r) {
    float s = 0.f;
#pragma unroll
    for (int ht = 0; ht < 4; ++ht) {
      float v = acc[ht][r];
      float lv = v >= 0.f ? v : 0.01f * v;
      s += lv * arv[ht];
    }
    ps[r] = s;
  }
#pragma unroll
  for (int msk = 1; msk < 16; msk <<= 1)
#pragma unroll
    for (int r = 0; r < 4; ++r) ps[r] += __shfl_xor(ps[r], msk);
  if (c == 0) {
#pragma unroll
    for (int r = 0; r < 4; ++r) sr[bh * N_ + nloc + 4 * g + r] = ps[r];
  }
  // frB[bh][jb][hd][kslot], kslot = 8g + 4t + r  (j_local = 16t + 4g + r)
#pragma unroll
  for (int ht = 0; ht < 4; ++ht)
#pragma unroll
    for (int r = 0; r < 4; ++r) {
      int hd = ht * 16 + c;
      frB[((bh * 64 + jb) * 64 + hd) * 32 + 8 * g + 4 * t + r] = f2bf(acc[ht][r]);
    }
}

// ---------------- flash attention, S^T form, in-register P, KV-split ----------------
// grid (32, 16, 2); block 256 = 4 waves; each wave 16 q-rows; NO LDS.
__global__ __launch_bounds__(256, 4) void k_attn(
    const unsigned short* __restrict__ rk, const unsigned short* __restrict__ rq,
    const float* __restrict__ sr, const unsigned short* __restrict__ frB,
    unsigned short* __restrict__ O0, unsigned short* __restrict__ O1,
    float2* __restrict__ ml) {
  const int tid = threadIdx.x;
  const int wave = tid >> 6, lane = tid & 63;
  const int c = lane & 15, g = lane >> 4;
  const int bh = blockIdx.y;
  const int b = bh >> 3, hh = bh & 7;
  const int z = blockIdx.z;
  const int qbase = blockIdx.x * 64 + wave * 16;

  // B-fragment: rk rows (cols i of S^T); k=16 slot holds 1.0 for the sr bias
  short8 b_rk = {0, 0, 0, 0, 0, 0, 0, 0};
  if (g < 2)
    b_rk = *reinterpret_cast<const short8*>(&rk[(bh * N_ + qbase + c) * 16 + 8 * g]);
  else if (g == 2)
    b_rk[0] = (short)0x3F80;  // bf16 1.0

  f32x4 O[4];
#pragma unroll
  for (int i = 0; i < 4; ++i) O[i] = (f32x4){0.f, 0.f, 0.f, 0.f};
  float m = -1e30f, l = 0.f;
  const unsigned short* frB_bh = frB + bh * 131072;

  for (int it = 0; it < 16; ++it) {
    const int j0 = z * 1024 + it * 64;
    f32x4 S[4];
#pragma unroll
    for (int jt = 0; jt < 4; ++jt) {
      const int jr = j0 + jt * 16 + c;
      short8 a = {0, 0, 0, 0, 0, 0, 0, 0};
      if (g < 2)
        a = *reinterpret_cast<const short8*>(&rq[(bh * N_ + jr) * 16 + 8 * g]);
      else if (g == 2)
        a[0] = (short)f2bf(sr[bh * N_ + jr]);
      f32x4 zz = {0.f, 0.f, 0.f, 0.f};
      S[jt] = __builtin_amdgcn_mfma_f32_16x16x32_bf16(a, b_rk, zz, 0, 0, 0);
    }
    // lane (c,g) holds S[q=c][j = j0+16jt+4g+r] — row-softmax for q-row c
    f32x4 mx;
#pragma unroll
    for (int r = 0; r < 4; ++r)
      mx[r] = fmaxf(fmaxf(S[0][r], S[1][r]), fmaxf(S[2][r], S[3][r]));
    float mm = fmaxf(fmaxf(mx[0], mx[1]), fmaxf(mx[2], mx[3]));
    mm = fmaxf(mm, __shfl_xor(mm, 16));
    mm = fmaxf(mm, __shfl_xor(mm, 32));
    const float mn = fmaxf(m, mm);
    const float sc = __expf(m - mn);
    float ps = 0.f;
#pragma unroll
    for (int jt = 0; jt < 4; ++jt)
#pragma unroll
      for (int r = 0; r < 4; ++r) {
        float pv = __expf(S[jt][r] - mn);
        S[jt][r] = pv;
        ps += pv;
      }
    ps += __shfl_xor(ps, 16);
    ps += __shfl_xor(ps, 32);
    l = l * sc + ps;
    m = mn;
    // redistribute sc (per q-row c) to O rows (4g+r)
    float scr[4];
#pragma unroll
    for (int r = 0; r < 4; ++r) scr[r] = __shfl(sc, 4 * g + r);
#pragma unroll
    for (int ht = 0; ht < 4; ++ht)
#pragma unroll
      for (int r = 0; r < 4; ++r) O[ht][r] *= scr[r];
    // pack P into A-fragments entirely in-register; PV
#pragma unroll
    for (int kk = 0; kk < 2; ++kk) {
      u32x4 pw;
      pw[0] = pack2(S[2 * kk][0], S[2 * kk][1]);
      pw[1] = pack2(S[2 * kk][2], S[2 * kk][3]);
      pw[2] = pack2(S[2 * kk + 1][0], S[2 * kk + 1][1]);
      pw[3] = pack2(S[2 * kk + 1][2], S[2 * kk + 1][3]);
      short8 pa = __builtin_bit_cast(short8, pw);
      const int jb = (j0 >> 5) + kk;
      const unsigned short* fp = frB_bh + jb * 2048 + 8 * g;
#pragma unroll
      for (int ht = 0; ht < 4; ++ht) {
        short8 bv = *reinterpret_cast<const short8*>(fp + (ht * 16 + c) * 32);
        O[ht] = __builtin_amdgcn_mfma_f32_16x16x32_bf16(pa, bv, O[ht], 0, 0, 0);
      }
    }
  }
  // epilogue: unnormalized O (bf16) + (m,l)
  unsigned short* Oz = z ? O1 : O0;
#pragma unroll
  for (int ht = 0; ht < 4; ++ht)
#pragma unroll
    for (int r = 0; r < 4; ++r) {
      const int n = qbase + 4 * g + r;
      Oz[(b * N_ + n) * 512 + hh * 64 + ht * 16 + c] = f2bf(O[ht][r]);
    }
  if (g == 0) {
    ml[(z * 16 + bh) * N_ + qbase + c] = make_float2(m, l);
  }
}

// ---------------- combine the two KV-splits -> ctxB bf16 (in place of O0) ----------------
__global__ __launch_bounds__(256) void k_combine(
    unsigned short* __restrict__ O0, const unsigned short* __restrict__ O1,
    const float2* __restrict__ ml) {
  const int idx = blockIdx.x * 256 + threadIdx.x;
  const int row = idx >> 7;
  const int q4 = (idx & 127) * 4;
  const int b = row >> 11, n = row & 2047;
  const int hh = q4 >> 6;
  const int bh = b * 8 + hh;
  const float2 ml0 = ml[bh * N_ + n];
  const float2 ml1 = ml[(16 + bh) * N_ + n];
  const float M = fmaxf(ml0.x, ml1.x);
  const float w0 = __expf(ml0.x - M), w1 = __expf(ml1.x - M);
  const float inv = 1.f / (w0 * ml0.y + w1 * ml1.y);
  const int off = row * 512 + q4;
  u32x2 v0 = *reinterpret_cast<const u32x2*>(&O0[off]);
  u32x2 v1 = *reinterpret_cast<const u32x2*>(&O1[off]);
  float o[4];
#pragma unroll
  for (int j = 0; j < 2; ++j) {
    o[2 * j] = (w0 * bf2f((unsigned short)(v0[j] & 0xffff)) +
                w1 * bf2f((unsigned short)(v1[j] & 0xffff))) * inv;
    o[2 * j + 1] = (w0 * bf2f((unsigned short)(v0[j] >> 16)) +
                    w1 * bf2f((unsigned short)(v1[j] >> 16))) * inv;
  }
  u32x2 ov;
  ov[0] = pack2(o[0], o[1]);
  ov[1] = pack2(o[2], o[3]);
  *reinterpret_cast<u32x2*>(&O0[off]) = ov;
}

// ---------------- x = ctxB @ WfT + h ; LayerNorm fused ----------------
// grid 256 blocks of 16 rows; 8 waves, wave w = col-tile w.
__global__ __launch_bounds__(512) void k_final(
    const unsigned short* __restrict__ ctxB, const unsigned short* __restrict__ WfT,
    const float* __restrict__ h, const float* __restrict__ gamma,
    const float* __restrict__ beta, float* __restrict__ out) {
  __shared__ float red[2][16][9];
  __shared__ float mur[16], rsr[16];
  const int tid = threadIdx.x;
  const int w = tid >> 6, lane = tid & 63;
  const int c = lane & 15, g = lane >> 4;
  const int rowbase = blockIdx.x * 16;

  f32x4 acc[4];
#pragma unroll
  for (int i = 0; i < 4; ++i) acc[i] = (f32x4){0.f, 0.f, 0.f, 0.f};

#pragma unroll 4
  for (int kt = 0; kt < 512; kt += 32) {
    short8 a = *reinterpret_cast<const short8*>(&ctxB[(rowbase + c) * 512 + kt + 8 * g]);
#pragma unroll
    for (int ht = 0; ht < 4; ++ht) {
      short8 bv = *reinterpret_cast<const short8*>(
          &WfT[(w * 64 + ht * 16 + c) * 512 + kt + 8 * g]);
      acc[ht] = __builtin_amdgcn_mfma_f32_16x16x32_bf16(a, bv, acc[ht], 0, 0, 0);
    }
  }
  // x = fh + h ; per-row stats
  float x[4][4];
  float px[4], pxx[4];
#pragma unroll
  for (int r = 0; r < 4; ++r) { px[r] = 0.f; pxx[r] = 0.f; }
#pragma unroll
  for (int ht = 0; ht < 4; ++ht)
#pragma unroll
    for (int r = 0; r < 4; ++r) {
      float v = acc[ht][r] + h[(rowbase + 4 * g + r) * 512 + w * 64 + ht * 16 + c];
      x[ht][r] = v;
      px[r] += v;
      pxx[r] += v * v;
    }
#pragma unroll
  for (int msk = 1; msk < 16; msk <<= 1)
#pragma unroll
    for (int r = 0; r < 4; ++r) {
      px[r] += __shfl_xor(px[r], msk);
      pxx[r] += __shfl_xor(pxx[r], msk);
    }
  if (c == 0) {
#pragma unroll
    for (int r = 0; r < 4; ++r) {
      red[0][4 * g + r][w] = px[r];
      red[1][4 * g + r][w] = pxx[r];
    }
  }
  __syncthreads();
  if (tid < 16) {
    float s = 0.f, sq = 0.f;
#pragma unroll
    for (int wv = 0; wv < 8; ++wv) { s += red[0][tid][wv]; sq += red[1][tid][wv]; }
    float mu = s * (1.f / 512.f);
    float var = sq * (1.f / 512.f) - mu * mu;
    mur[tid] = mu;
    rsr[tid] = rsqrtf(var + 1e-5f);
  }
  __syncthreads();
#pragma unroll
  for (int ht = 0; ht < 4; ++ht)
#pragma unroll
    for (int r = 0; r < 4; ++r) {
      const int col = w * 64 + ht * 16 + c;
      const float mu = mur[4 * g + r], rs = rsr[4 * g + r];
      out[(rowbase + 4 * g + r) * 512 + col] =
          (x[ht][r] - mu) * rs * gamma[col] + beta[col];
    }
}

extern "C" void kernel_launch(void* const* d_in, const int* in_sizes, int n_in,
                              void* d_out, int out_size, void* d_ws, size_t ws_size,
                              hipStream_t stream) {
  const float* h     = (const float*)d_in[0];
  const float* rh    = (const float*)d_in[1];
  // d_in[2] = Wl, d_in[4] = al: dead (softmax shift-invariance along j)
  const float* Wr    = (const float*)d_in[3];
  const float* ar    = (const float*)d_in[5];
  const float* Wrs   = (const float*)d_in[6];
  const float* Wrt   = (const float*)d_in[7];
  const float* Wf    = (const float*)d_in[8];
  const float* gamma = (const float*)d_in[9];
  const float* beta  = (const float*)d_in[10];

  const size_t MB = 1ull << 20;
  char* ws = (char*)d_ws;
  unsigned short* frB = (unsigned short*)(ws);                    // 4 MB
  unsigned short* rk  = (unsigned short*)(ws + 4 * MB);           // 1 MB
  unsigned short* rq  = (unsigned short*)(ws + 5 * MB);           // 1 MB
  float*          sr  = (float*)(ws + 6 * MB);                    // 128 KB
  float2*         ml  = (float2*)(ws + 6 * MB + 256 * 1024);      // 512 KB
  unsigned short* hB  = (unsigned short*)(ws + 7 * MB);           // 4 MB
  unsigned short* WrT = (unsigned short*)(ws + 11 * MB);          // 512 KB
  unsigned short* WfT = (unsigned short*)(ws + 11 * MB + 512 * 1024);  // 512 KB
  unsigned short* O0  = (unsigned short*)(ws + 12 * MB);          // 4 MB (→ ctxB)
  unsigned short* O1  = (unsigned short*)(ws + 16 * MB);          // 4 MB   total 20 MB

  hipLaunchKernelGGL(k_cast_h, dim3(1024), dim3(256), 0, stream, h, hB);
  hipLaunchKernelGGL(k_cast_wT, dim3(16, 16, 2), dim3(256), 0, stream, Wr, Wf, WrT, WfT);
  hipLaunchKernelGGL(k_projr, dim3(2048), dim3(256), 0, stream, rh, Wrs, Wrt, rk, rq);
  hipLaunchKernelGGL(k_proj_fr, dim3(256), dim3(512), 0, stream, hB, WrT, ar, frB, sr);
  hipLaunchKernelGGL(k_attn, dim3(32, 16, 2), dim3(256), 0, stream, rk, rq, sr, frB, O0, O1, ml);
  hipLaunchKernelGGL(k_combine, dim3(2048), dim3(256), 0, stream, O0, O1, ml);
  hipLaunchKernelGGL(k_final, dim3(256), dim3(512), 0, stream, O0, WfT, h, gamma, beta, (float*)d_out);
}

// Round 4
// 197.303 us; speedup vs baseline: 1.1470x; 1.0037x over previous
//
#include <hip/hip_runtime.h>
#include <hip/hip_bf16.h>

typedef __attribute__((ext_vector_type(8))) short short8;
typedef __attribute__((ext_vector_type(4))) float f32x4;
typedef __attribute__((ext_vector_type(4))) unsigned int u32x4;
typedef __attribute__((ext_vector_type(2))) unsigned int u32x2;

#define N_ 2048

__device__ __forceinline__ unsigned short f2bf(float f) {
  return __builtin_bit_cast(unsigned short, __float2bfloat16(f));
}
__device__ __forceinline__ float bf2f(unsigned short u) {
  return __builtin_bit_cast(float, ((unsigned int)u) << 16);
}
__device__ __forceinline__ unsigned int pack2(float lo, float hi) {
  return ((unsigned int)f2bf(hi) << 16) | (unsigned int)f2bf(lo);
}

// ---------------- transpose-cast Wr, Wf -> WrT, WfT (bf16 [col][k]) ----------------
__global__ __launch_bounds__(256) void k_cast_wT(const float* __restrict__ Wr,
                                                 const float* __restrict__ Wf,
                                                 unsigned short* __restrict__ WrT,
                                                 unsigned short* __restrict__ WfT) {
  const float* W = blockIdx.z ? Wf : Wr;
  unsigned short* WT = blockIdx.z ? WfT : WrT;
  __shared__ float t[32][33];
  const int kt = blockIdx.x * 32, ct = blockIdx.y * 32;
  const int r = threadIdx.x >> 3, c4 = (threadIdx.x & 7) * 4;
  f32x4 v = *reinterpret_cast<const f32x4*>(&W[(kt + r) * 512 + ct + c4]);
#pragma unroll
  for (int j = 0; j < 4; ++j) t[r][c4 + j] = v[j];
  __syncthreads();
  u32x2 o;
  o[0] = pack2(t[c4][r], t[c4 + 1][r]);
  o[1] = pack2(t[c4 + 2][r], t[c4 + 3][r]);
  *reinterpret_cast<u32x2*>(&WT[(ct + r) * 512 + kt + c4]) = o;
}

// ---------------- rk = rh @ Wrs, rq = rh @ Wrt (bf16, [bh][n][16]) ----------------
__global__ __launch_bounds__(256) void k_projr(
    const float* __restrict__ rh, const float* __restrict__ Wrs,
    const float* __restrict__ Wrt,
    unsigned short* __restrict__ rk, unsigned short* __restrict__ rq) {
  const int tid = threadIdx.x;
  const int col = tid & 127;
  const int ro = tid >> 7;
  const int nf = blockIdx.x * 2 + ro;
  const f32x4* src = reinterpret_cast<const f32x4*>(&rh[nf * 16]);
  f32x4 rv[4] = {src[0], src[1], src[2], src[3]};
  float sk = 0.f, sq = 0.f;
#pragma unroll
  for (int k4 = 0; k4 < 4; ++k4)
#pragma unroll
    for (int j = 0; j < 4; ++j) {
      float v = rv[k4][j];
      int k = k4 * 4 + j;
      sk += v * Wrs[k * 128 + col];
      sq += v * Wrt[k * 128 + col];
    }
  int bb = nf >> 11, n = nf & 2047, hh = col >> 4, r = col & 15;
  int oidx = ((bb * 8 + hh) * N_ + n) * 16 + r;
  rk[oidx] = f2bf(sk);
  rq[oidx] = f2bf(sq);
}

// ---------------- fr = h @ WrT (MFMA, fused f32->bf16 cast); sr; frB ----------------
// grid 256 blocks of 16 rows; 8 waves, wave w = head w (64 cols).
__global__ __launch_bounds__(512) void k_proj_fr(
    const float* __restrict__ h, const unsigned short* __restrict__ WrT,
    const float* __restrict__ ar,
    unsigned short* __restrict__ frB, float* __restrict__ sr) {
  const int tid = threadIdx.x;
  const int w = tid >> 6, lane = tid & 63;
  const int c = lane & 15, g = lane >> 4;
  const int rowbase = blockIdx.x * 16;

  f32x4 acc[4];
#pragma unroll
  for (int i = 0; i < 4; ++i) acc[i] = (f32x4){0.f, 0.f, 0.f, 0.f};

#pragma unroll 4
  for (int kt = 0; kt < 512; kt += 32) {
    const float* hp = &h[(rowbase + c) * 512 + kt + 8 * g];
    f32x4 h0 = *reinterpret_cast<const f32x4*>(hp);
    f32x4 h1 = *reinterpret_cast<const f32x4*>(hp + 4);
    u32x4 aw;
    aw[0] = pack2(h0[0], h0[1]);
    aw[1] = pack2(h0[2], h0[3]);
    aw[2] = pack2(h1[0], h1[1]);
    aw[3] = pack2(h1[2], h1[3]);
    short8 a = __builtin_bit_cast(short8, aw);
#pragma unroll
    for (int ht = 0; ht < 4; ++ht) {
      short8 bv = *reinterpret_cast<const short8*>(
          &WrT[(w * 64 + ht * 16 + c) * 512 + kt + 8 * g]);
      acc[ht] = __builtin_amdgcn_mfma_f32_16x16x32_bf16(a, bv, acc[ht], 0, 0, 0);
    }
  }

  const int b = rowbase >> 11;
  const int bh = b * 8 + w;
  const int nloc = rowbase & 2047;
  const int jb = nloc >> 5;
  const int t = (nloc >> 4) & 1;

  float arv[4];
#pragma unroll
  for (int ht = 0; ht < 4; ++ht) arv[ht] = ar[ht * 16 + c];

  float ps[4];
#pragma unroll
  for (int r = 0; r < 4; ++r) {
    float s = 0.f;
#pragma unroll
    for (int ht = 0; ht < 4; ++ht) {
      float v = acc[ht][r];
      float lv = v >= 0.f ? v : 0.01f * v;
      s += lv * arv[ht];
    }
    ps[r] = s;
  }
#pragma unroll
  for (int msk = 1; msk < 16; msk <<= 1)
#pragma unroll
    for (int r = 0; r < 4; ++r) ps[r] += __shfl_xor(ps[r], msk);
  if (c == 0) {
#pragma unroll
    for (int r = 0; r < 4; ++r) sr[bh * N_ + nloc + 4 * g + r] = ps[r];
  }
  // frB[bh][jb][hd][kslot], kslot = 8g + 4t + r  (j_local = 16t + 4g + r)
#pragma unroll
  for (int ht = 0; ht < 4; ++ht)
#pragma unroll
    for (int r = 0; r < 4; ++r) {
      int hd = ht * 16 + c;
      frB[((bh * 64 + jb) * 64 + hd) * 32 + 8 * g + 4 * t + r] = f2bf(acc[ht][r]);
    }
}

// ---------------- flash attention, S^T form, in-register P, KV-split x4 ----------------
// grid (32, 16, 4); block 256 = 4 waves; each wave 16 q-rows x 512 j; NO LDS.
__global__ __launch_bounds__(256, 4) void k_attn(
    const unsigned short* __restrict__ rk, const unsigned short* __restrict__ rq,
    const float* __restrict__ sr, const unsigned short* __restrict__ frB,
    unsigned short* __restrict__ O0, unsigned short* __restrict__ O1,
    unsigned short* __restrict__ O2, unsigned short* __restrict__ O3,
    float2* __restrict__ ml) {
  const int tid = threadIdx.x;
  const int wave = tid >> 6, lane = tid & 63;
  const int c = lane & 15, g = lane >> 4;
  const int bh = blockIdx.y;
  const int b = bh >> 3, hh = bh & 7;
  const int z = blockIdx.z;
  const int qbase = blockIdx.x * 64 + wave * 16;

  // B-fragment: rk rows (cols i of S^T); k=16 slot holds 1.0 for the sr bias
  short8 b_rk = {0, 0, 0, 0, 0, 0, 0, 0};
  if (g < 2)
    b_rk = *reinterpret_cast<const short8*>(&rk[(bh * N_ + qbase + c) * 16 + 8 * g]);
  else if (g == 2)
    b_rk[0] = (short)0x3F80;  // bf16 1.0

  f32x4 O[4];
#pragma unroll
  for (int i = 0; i < 4; ++i) O[i] = (f32x4){0.f, 0.f, 0.f, 0.f};
  float m = -1e30f, l = 0.f;
  const unsigned short* frB_bh = frB + bh * 131072;

  for (int it = 0; it < 4; ++it) {
    const int j0 = z * 512 + it * 128;
    f32x4 S[8];
#pragma unroll
    for (int jh = 0; jh < 8; ++jh) {
      const int jr = j0 + jh * 16 + c;
      short8 a = {0, 0, 0, 0, 0, 0, 0, 0};
      if (g < 2)
        a = *reinterpret_cast<const short8*>(&rq[(bh * N_ + jr) * 16 + 8 * g]);
      else if (g == 2)
        a[0] = (short)f2bf(sr[bh * N_ + jr]);
      f32x4 zz = {0.f, 0.f, 0.f, 0.f};
      S[jh] = __builtin_amdgcn_mfma_f32_16x16x32_bf16(a, b_rk, zz, 0, 0, 0);
    }
    // lane (c,g) holds S[q=c][j = j0+16jh+4g+r] — row-softmax for q-row c
    f32x4 mx = S[0];
#pragma unroll
    for (int jh = 1; jh < 8; ++jh)
#pragma unroll
      for (int r = 0; r < 4; ++r) mx[r] = fmaxf(mx[r], S[jh][r]);
    float mm = fmaxf(fmaxf(mx[0], mx[1]), fmaxf(mx[2], mx[3]));
    mm = fmaxf(mm, __shfl_xor(mm, 16));
    mm = fmaxf(mm, __shfl_xor(mm, 32));
    const float mn = fmaxf(m, mm);
    const float sc = __expf(m - mn);
    f32x4 pv = {0.f, 0.f, 0.f, 0.f};
#pragma unroll
    for (int jh = 0; jh < 8; ++jh)
#pragma unroll
      for (int r = 0; r < 4; ++r) {
        float e = __expf(S[jh][r] - mn);
        S[jh][r] = e;
        pv[r] += e;
      }
    float ps = (pv[0] + pv[1]) + (pv[2] + pv[3]);
    ps += __shfl_xor(ps, 16);
    ps += __shfl_xor(ps, 32);
    l = l * sc + ps;
    m = mn;
    // redistribute sc (per q-row c) to O rows (4g+r)
    float scr[4];
#pragma unroll
    for (int r = 0; r < 4; ++r) scr[r] = __shfl(sc, 4 * g + r);
#pragma unroll
    for (int ht = 0; ht < 4; ++ht)
#pragma unroll
      for (int r = 0; r < 4; ++r) O[ht][r] *= scr[r];
    // pack P into A-fragments entirely in-register; PV
#pragma unroll
    for (int kk = 0; kk < 4; ++kk) {
      u32x4 pw;
      pw[0] = pack2(S[2 * kk][0], S[2 * kk][1]);
      pw[1] = pack2(S[2 * kk][2], S[2 * kk][3]);
      pw[2] = pack2(S[2 * kk + 1][0], S[2 * kk + 1][1]);
      pw[3] = pack2(S[2 * kk + 1][2], S[2 * kk + 1][3]);
      short8 pa = __builtin_bit_cast(short8, pw);
      const int jb = (j0 >> 5) + kk;
      const unsigned short* fp = frB_bh + jb * 2048 + 8 * g;
#pragma unroll
      for (int ht = 0; ht < 4; ++ht) {
        short8 bv = *reinterpret_cast<const short8*>(fp + (ht * 16 + c) * 32);
        O[ht] = __builtin_amdgcn_mfma_f32_16x16x32_bf16(pa, bv, O[ht], 0, 0, 0);
      }
    }
  }
  // epilogue: unnormalized O (bf16) + (m,l)
  unsigned short* Oz = (z == 0) ? O0 : (z == 1) ? O1 : (z == 2) ? O2 : O3;
#pragma unroll
  for (int ht = 0; ht < 4; ++ht)
#pragma unroll
    for (int r = 0; r < 4; ++r) {
      const int n = qbase + 4 * g + r;
      Oz[(b * N_ + n) * 512 + hh * 64 + ht * 16 + c] = f2bf(O[ht][r]);
    }
  if (g == 0) {
    ml[(z * 16 + bh) * N_ + qbase + c] = make_float2(m, l);
  }
}

// ---------------- combine 4 KV-splits -> ctxB bf16 (over dead frB region) ----------------
__global__ __launch_bounds__(256) void k_combine(
    const unsigned short* __restrict__ O0, const unsigned short* __restrict__ O1,
    const unsigned short* __restrict__ O2, const unsigned short* __restrict__ O3,
    const float2* __restrict__ ml, unsigned short* __restrict__ ctx) {
  const int idx = blockIdx.x * 256 + threadIdx.x;
  const int row = idx >> 6;
  const int c8 = (idx & 63) * 8;
  const int b = row >> 11, n = row & 2047;
  const int hh = c8 >> 6;
  const int bh = b * 8 + hh;
  float2 mlv[4];
#pragma unroll
  for (int zz = 0; zz < 4; ++zz) mlv[zz] = ml[(zz * 16 + bh) * N_ + n];
  float M = fmaxf(fmaxf(mlv[0].x, mlv[1].x), fmaxf(mlv[2].x, mlv[3].x));
  float wgt[4];
  float denom = 0.f;
#pragma unroll
  for (int zz = 0; zz < 4; ++zz) {
    wgt[zz] = __expf(mlv[zz].x - M);
    denom += wgt[zz] * mlv[zz].y;
  }
  const float inv = 1.f / denom;
  const int off = row * 512 + c8;
  u32x4 v[4];
  v[0] = *reinterpret_cast<const u32x4*>(&O0[off]);
  v[1] = *reinterpret_cast<const u32x4*>(&O1[off]);
  v[2] = *reinterpret_cast<const u32x4*>(&O2[off]);
  v[3] = *reinterpret_cast<const u32x4*>(&O3[off]);
  u32x4 ov;
#pragma unroll
  for (int j = 0; j < 4; ++j) {
    float lo = 0.f, hi = 0.f;
#pragma unroll
    for (int zz = 0; zz < 4; ++zz) {
      lo += wgt[zz] * bf2f((unsigned short)(v[zz][j] & 0xffff));
      hi += wgt[zz] * bf2f((unsigned short)(v[zz][j] >> 16));
    }
    ov[j] = pack2(lo * inv, hi * inv);
  }
  *reinterpret_cast<u32x4*>(&ctx[off]) = ov;
}

// ---------------- x = ctxB @ WfT + h ; LayerNorm fused ----------------
// grid 256 blocks of 16 rows; 8 waves, wave w = col-tile w.
__global__ __launch_bounds__(512) void k_final(
    const unsigned short* __restrict__ ctxB, const unsigned short* __restrict__ WfT,
    const float* __restrict__ h, const float* __restrict__ gamma,
    const float* __restrict__ beta, float* __restrict__ out) {
  __shared__ float red[2][16][9];
  __shared__ float mur[16], rsr[16];
  const int tid = threadIdx.x;
  const int w = tid >> 6, lane = tid & 63;
  const int c = lane & 15, g = lane >> 4;
  const int rowbase = blockIdx.x * 16;

  f32x4 acc[4];
#pragma unroll
  for (int i = 0; i < 4; ++i) acc[i] = (f32x4){0.f, 0.f, 0.f, 0.f};

#pragma unroll 4
  for (int kt = 0; kt < 512; kt += 32) {
    short8 a = *reinterpret_cast<const short8*>(&ctxB[(rowbase + c) * 512 + kt + 8 * g]);
#pragma unroll
    for (int ht = 0; ht < 4; ++ht) {
      short8 bv = *reinterpret_cast<const short8*>(
          &WfT[(w * 64 + ht * 16 + c) * 512 + kt + 8 * g]);
      acc[ht] = __builtin_amdgcn_mfma_f32_16x16x32_bf16(a, bv, acc[ht], 0, 0, 0);
    }
  }
  // x = fh + h ; per-row stats
  float x[4][4];
  float px[4], pxx[4];
#pragma unroll
  for (int r = 0; r < 4; ++r) { px[r] = 0.f; pxx[r] = 0.f; }
#pragma unroll
  for (int ht = 0; ht < 4; ++ht)
#pragma unroll
    for (int r = 0; r < 4; ++r) {
      float v = acc[ht][r] + h[(rowbase + 4 * g + r) * 512 + w * 64 + ht * 16 + c];
      x[ht][r] = v;
      px[r] += v;
      pxx[r] += v * v;
    }
#pragma unroll
  for (int msk = 1; msk < 16; msk <<= 1)
#pragma unroll
    for (int r = 0; r < 4; ++r) {
      px[r] += __shfl_xor(px[r], msk);
      pxx[r] += __shfl_xor(pxx[r], msk);
    }
  if (c == 0) {
#pragma unroll
    for (int r = 0; r < 4; ++r) {
      red[0][4 * g + r][w] = px[r];
      red[1][4 * g + r][w] = pxx[r];
    }
  }
  __syncthreads();
  if (tid < 16) {
    float s = 0.f, sq = 0.f;
#pragma unroll
    for (int wv = 0; wv < 8; ++wv) { s += red[0][tid][wv]; sq += red[1][tid][wv]; }
    float mu = s * (1.f / 512.f);
    float var = sq * (1.f / 512.f) - mu * mu;
    mur[tid] = mu;
    rsr[tid] = rsqrtf(var + 1e-5f);
  }
  __syncthreads();
#pragma unroll
  for (int ht = 0; ht < 4; ++ht)
#pragma unroll
    for (int r = 0; r < 4; ++r) {
      const int col = w * 64 + ht * 16 + c;
      const float mu = mur[4 * g + r], rs = rsr[4 * g + r];
      out[(rowbase + 4 * g + r) * 512 + col] =
          (x[ht][r] - mu) * rs * gamma[col] + beta[col];
    }
}

extern "C" void kernel_launch(void* const* d_in, const int* in_sizes, int n_in,
                              void* d_out, int out_size, void* d_ws, size_t ws_size,
                              hipStream_t stream) {
  const float* h     = (const float*)d_in[0];
  const float* rh    = (const float*)d_in[1];
  // d_in[2] = Wl, d_in[4] = al: dead (softmax shift-invariance along j)
  const float* Wr    = (const float*)d_in[3];
  const float* ar    = (const float*)d_in[5];
  const float* Wrs   = (const float*)d_in[6];
  const float* Wrt   = (const float*)d_in[7];
  const float* Wf    = (const float*)d_in[8];
  const float* gamma = (const float*)d_in[9];
  const float* beta  = (const float*)d_in[10];

  const size_t MB = 1ull << 20;
  char* ws = (char*)d_ws;
  unsigned short* frB = (unsigned short*)(ws);                         // 4 MB (→ ctxB)
  unsigned short* rk  = (unsigned short*)(ws + 4 * MB);                // 1 MB
  unsigned short* rq  = (unsigned short*)(ws + 5 * MB);                // 1 MB
  float*          sr  = (float*)(ws + 6 * MB);                         // 128 KB
  float2*         ml  = (float2*)(ws + 6 * MB + 256 * 1024);           // 1 MB
  unsigned short* WrT = (unsigned short*)(ws + 7 * MB + 256 * 1024);   // 512 KB
  unsigned short* WfT = (unsigned short*)(ws + 7 * MB + 768 * 1024);   // 512 KB
  unsigned short* O0  = (unsigned short*)(ws + 8 * MB + 256 * 1024);   // 4 MB
  unsigned short* O1  = (unsigned short*)(ws + 12 * MB + 256 * 1024);  // 4 MB (16.25 MB)
  unsigned short* O2  = (unsigned short*)d_out;                        // 4 MB (scratch)
  unsigned short* O3  = (unsigned short*)((char*)d_out + 4 * MB);      // 4 MB (scratch)

  hipLaunchKernelGGL(k_cast_wT, dim3(16, 16, 2), dim3(256), 0, stream, Wr, Wf, WrT, WfT);
  hipLaunchKernelGGL(k_projr, dim3(1024), dim3(256), 0, stream, rh, Wrs, Wrt, rk, rq);
  hipLaunchKernelGGL(k_proj_fr, dim3(256), dim3(512), 0, stream, h, WrT, ar, frB, sr);
  hipLaunchKernelGGL(k_attn, dim3(32, 16, 4), dim3(256), 0, stream, rk, rq, sr, frB,
                     O0, O1, O2, O3, ml);
  hipLaunchKernelGGL(k_combine, dim3(1024), dim3(256), 0, stream, O0, O1, O2, O3, ml, frB);
  hipLaunchKernelGGL(k_final, dim3(256), dim3(512), 0, stream, frB, WfT, h, gamma, beta,
                     (float*)d_out);
}

// Round 7
// 185.827 us; speedup vs baseline: 1.2178x; 1.0618x over previous
//
#include <hip/hip_runtime.h>
#include <hip/hip_bf16.h>

typedef __attribute__((ext_vector_type(8))) short short8;
typedef __attribute__((ext_vector_type(4))) float f32x4;
typedef __attribute__((ext_vector_type(4))) unsigned int u32x4;
typedef __attribute__((ext_vector_type(2))) unsigned int u32x2;

#define N_ 2048

__device__ __forceinline__ unsigned short f2bf(float f) {
  return __builtin_bit_cast(unsigned short, __float2bfloat16(f));
}
__device__ __forceinline__ float bf2f(unsigned short u) {
  return __builtin_bit_cast(float, ((unsigned int)u) << 16);
}
__device__ __forceinline__ unsigned int pack2(float lo, float hi) {
  return ((unsigned int)f2bf(hi) << 16) | (unsigned int)f2bf(lo);
}

// ---------------- transpose-cast Wr, Wf -> WrT, WfT (bf16 [col][k]) ----------------
__global__ __launch_bounds__(256) void k_cast_wT(const float* __restrict__ Wr,
                                                 const float* __restrict__ Wf,
                                                 unsigned short* __restrict__ WrT,
                                                 unsigned short* __restrict__ WfT) {
  const float* W = blockIdx.z ? Wf : Wr;
  unsigned short* WT = blockIdx.z ? WfT : WrT;
  __shared__ float t[32][33];
  const int kt = blockIdx.x * 32, ct = blockIdx.y * 32;
  const int r = threadIdx.x >> 3, c4 = (threadIdx.x & 7) * 4;
  f32x4 v = *reinterpret_cast<const f32x4*>(&W[(kt + r) * 512 + ct + c4]);
#pragma unroll
  for (int j = 0; j < 4; ++j) t[r][c4 + j] = v[j];
  __syncthreads();
  u32x2 o;
  o[0] = pack2(t[c4][r], t[c4 + 1][r]);
  o[1] = pack2(t[c4 + 2][r], t[c4 + 3][r]);
  *reinterpret_cast<u32x2*>(&WT[(ct + r) * 512 + kt + c4]) = o;
}

// ---------------- rk = rh @ Wrs, rq = rh @ Wrt (bf16, [bh][n][16]) ----------------
__global__ __launch_bounds__(256) void k_projr(
    const float* __restrict__ rh, const float* __restrict__ Wrs,
    const float* __restrict__ Wrt,
    unsigned short* __restrict__ rk, unsigned short* __restrict__ rq) {
  const int tid = threadIdx.x;
  const int col = tid & 127;
  const int ro = tid >> 7;
  const int nf = blockIdx.x * 2 + ro;
  const f32x4* src = reinterpret_cast<const f32x4*>(&rh[nf * 16]);
  f32x4 rv[4] = {src[0], src[1], src[2], src[3]};
  float sk = 0.f, sq = 0.f;
#pragma unroll
  for (int k4 = 0; k4 < 4; ++k4)
#pragma unroll
    for (int j = 0; j < 4; ++j) {
      float v = rv[k4][j];
      int k = k4 * 4 + j;
      sk += v * Wrs[k * 128 + col];
      sq += v * Wrt[k * 128 + col];
    }
  int bb = nf >> 11, n = nf & 2047, hh = col >> 4, r = col & 15;
  int oidx = ((bb * 8 + hh) * N_ + n) * 16 + r;
  rk[oidx] = f2bf(sk);
  rq[oidx] = f2bf(sq);
}

// ---------------- fr = h @ WrT (MFMA, fused cast); sr; frB (k-permuted) ----------------
// grid (256, 2); block 256 = 4 waves; wave w -> head blockIdx.y*4+w; 16 rows/block.
__global__ __launch_bounds__(256) void k_proj_fr(
    const float* __restrict__ h, const unsigned short* __restrict__ WrT,
    const float* __restrict__ ar,
    unsigned short* __restrict__ frB, float* __restrict__ sr) {
  const int tid = threadIdx.x;
  const int w = tid >> 6, lane = tid & 63;
  const int c = lane & 15, g = lane >> 4;
  const int rowbase = blockIdx.x * 16;
  const int hh = blockIdx.y * 4 + w;

  f32x4 acc[4];
#pragma unroll
  for (int i = 0; i < 4; ++i) acc[i] = (f32x4){0.f, 0.f, 0.f, 0.f};

#pragma unroll 4
  for (int kt = 0; kt < 512; kt += 32) {
    const float* hp = &h[(rowbase + c) * 512 + kt + 8 * g];
    f32x4 h0 = *reinterpret_cast<const f32x4*>(hp);
    f32x4 h1 = *reinterpret_cast<const f32x4*>(hp + 4);
    u32x4 aw;
    aw[0] = pack2(h0[0], h0[1]);
    aw[1] = pack2(h0[2], h0[3]);
    aw[2] = pack2(h1[0], h1[1]);
    aw[3] = pack2(h1[2], h1[3]);
    short8 a = __builtin_bit_cast(short8, aw);
#pragma unroll
    for (int ht = 0; ht < 4; ++ht) {
      short8 bv = *reinterpret_cast<const short8*>(
          &WrT[(hh * 64 + ht * 16 + c) * 512 + kt + 8 * g]);
      acc[ht] = __builtin_amdgcn_mfma_f32_16x16x32_bf16(a, bv, acc[ht], 0, 0, 0);
    }
  }

  const int b = rowbase >> 11;
  const int bh = b * 8 + hh;
  const int nloc = rowbase & 2047;
  const int jb = nloc >> 5;
  const int t = (nloc >> 4) & 1;

  float arv[4];
#pragma unroll
  for (int ht = 0; ht < 4; ++ht) arv[ht] = ar[ht * 16 + c];

  float ps[4];
#pragma unroll
  for (int r = 0; r < 4; ++r) {
    float s = 0.f;
#pragma unroll
    for (int ht = 0; ht < 4; ++ht) {
      float v = acc[ht][r];
      float lv = v >= 0.f ? v : 0.01f * v;
      s += lv * arv[ht];
    }
    ps[r] = s;
  }
#pragma unroll
  for (int msk = 1; msk < 16; msk <<= 1)
#pragma unroll
    for (int r = 0; r < 4; ++r) ps[r] += __shfl_xor(ps[r], msk);
  if (c == 0) {
#pragma unroll
    for (int r = 0; r < 4; ++r) sr[bh * N_ + nloc + 4 * g + r] = ps[r];
  }
  // frB[bh][jb][hd][kslot], kslot = 8g + 4t + r  (j_local = 16t + 4g + r)
#pragma unroll
  for (int ht = 0; ht < 4; ++ht) {
    int hd = ht * 16 + c;
    u32x2 ov;
    ov[0] = pack2(acc[ht][0], acc[ht][1]);
    ov[1] = pack2(acc[ht][2], acc[ht][3]);
    *reinterpret_cast<u32x2*>(
        &frB[((bh * 64 + jb) * 64 + hd) * 32 + 8 * g + 4 * t]) = ov;
  }
}

// ---------------- flash attention, m=0 exact softmax, q=32/wave, KV-split x4 ----------------
// grid (32, 16, 4); block 128 = 2 waves; NO LDS, NO barriers, no cross-lane until epilogue.
__global__ __launch_bounds__(128) void k_attn(
    const unsigned short* __restrict__ rk, const unsigned short* __restrict__ rq,
    const float* __restrict__ sr, const unsigned short* __restrict__ frB,
    unsigned short* __restrict__ O0, unsigned short* __restrict__ O1,
    unsigned short* __restrict__ O2, unsigned short* __restrict__ O3,
    float* __restrict__ lbuf) {
  const int tid = threadIdx.x;
  const int wave = tid >> 6, lane = tid & 63;
  const int c = lane & 15, g = lane >> 4;
  const int bh = blockIdx.y;
  const int b = bh >> 3, hh = bh & 7;
  const int z = blockIdx.z;
  const int qbase = blockIdx.x * 64 + wave * 32;

  // B-fragments for the two q-halves; k=16 pad slot carries 1.0 (sr bias column)
  short8 brk0 = {0, 0, 0, 0, 0, 0, 0, 0};
  short8 brk1 = {0, 0, 0, 0, 0, 0, 0, 0};
  if (g < 2) {
    brk0 = *reinterpret_cast<const short8*>(&rk[(bh * N_ + qbase + c) * 16 + 8 * g]);
    brk1 = *reinterpret_cast<const short8*>(&rk[(bh * N_ + qbase + 16 + c) * 16 + 8 * g]);
  } else if (g == 2) {
    brk0[0] = (short)0x3F80;
    brk1[0] = (short)0x3F80;
  }

  f32x4 O[2][4];
#pragma unroll
  for (int q = 0; q < 2; ++q)
#pragma unroll
    for (int i = 0; i < 4; ++i) O[q][i] = (f32x4){0.f, 0.f, 0.f, 0.f};
  float lacc0 = 0.f, lacc1 = 0.f;
  const unsigned short* frB_bh = frB + bh * 131072;

  for (int it = 0; it < 4; ++it) {
    const int j0 = z * 512 + it * 128;
    f32x4 S0[8], S1[8];
#pragma unroll
    for (int jh = 0; jh < 8; ++jh) {
      const int jr = j0 + jh * 16 + c;
      short8 a = {0, 0, 0, 0, 0, 0, 0, 0};
      if (g < 2)
        a = *reinterpret_cast<const short8*>(&rq[(bh * N_ + jr) * 16 + 8 * g]);
      else if (g == 2)
        a[0] = (short)f2bf(sr[bh * N_ + jr]);
      f32x4 zz = {0.f, 0.f, 0.f, 0.f};
      S0[jh] = __builtin_amdgcn_mfma_f32_16x16x32_bf16(a, brk0, zz, 0, 0, 0);
      S1[jh] = __builtin_amdgcn_mfma_f32_16x16x32_bf16(a, brk1, zz, 0, 0, 0);
    }
    // exact softmax with fixed shift 0: scores bounded ~|0.5| by construction
#pragma unroll
    for (int jh = 0; jh < 8; ++jh)
#pragma unroll
      for (int r = 0; r < 4; ++r) {
        float e0 = __expf(S0[jh][r]);
        S0[jh][r] = e0;
        lacc0 += e0;
        float e1 = __expf(S1[jh][r]);
        S1[jh][r] = e1;
        lacc1 += e1;
      }
    // pack P into A-fragments in-register; PV for both halves sharing bv loads
#pragma unroll
    for (int kk = 0; kk < 4; ++kk) {
      u32x4 p0, p1;
      p0[0] = pack2(S0[2 * kk][0], S0[2 * kk][1]);
      p0[1] = pack2(S0[2 * kk][2], S0[2 * kk][3]);
      p0[2] = pack2(S0[2 * kk + 1][0], S0[2 * kk + 1][1]);
      p0[3] = pack2(S0[2 * kk + 1][2], S0[2 * kk + 1][3]);
      p1[0] = pack2(S1[2 * kk][0], S1[2 * kk][1]);
      p1[1] = pack2(S1[2 * kk][2], S1[2 * kk][3]);
      p1[2] = pack2(S1[2 * kk + 1][0], S1[2 * kk + 1][1]);
      p1[3] = pack2(S1[2 * kk + 1][2], S1[2 * kk + 1][3]);
      short8 pa0 = __builtin_bit_cast(short8, p0);
      short8 pa1 = __builtin_bit_cast(short8, p1);
      const int jb = (j0 >> 5) + kk;
      const unsigned short* fp = frB_bh + jb * 2048 + 8 * g;
#pragma unroll
      for (int ht = 0; ht < 4; ++ht) {
        short8 bv = *reinterpret_cast<const short8*>(fp + (ht * 16 + c) * 32);
        O[0][ht] = __builtin_amdgcn_mfma_f32_16x16x32_bf16(pa0, bv, O[0][ht], 0, 0, 0);
        O[1][ht] = __builtin_amdgcn_mfma_f32_16x16x32_bf16(pa1, bv, O[1][ht], 0, 0, 0);
      }
    }
  }
  // epilogue: reduce l over g-groups (rows are per-c), store unnormalized O + l
  lacc0 += __shfl_xor(lacc0, 16);
  lacc0 += __shfl_xor(lacc0, 32);
  lacc1 += __shfl_xor(lacc1, 16);
  lacc1 += __shfl_xor(lacc1, 32);
  if (g == 0) {
    lbuf[(z * 16 + bh) * N_ + qbase + c] = lacc0;
    lbuf[(z * 16 + bh) * N_ + qbase + 16 + c] = lacc1;
  }
  unsigned short* Oz = (z == 0) ? O0 : (z == 1) ? O1 : (z == 2) ? O2 : O3;
#pragma unroll
  for (int q = 0; q < 2; ++q)
#pragma unroll
    for (int ht = 0; ht < 4; ++ht)
#pragma unroll
      for (int r = 0; r < 4; ++r) {
        const int n = qbase + q * 16 + 4 * g + r;
        Oz[(b * N_ + n) * 512 + hh * 64 + ht * 16 + c] = f2bf(O[q][ht][r]);
      }
}

// ---------------- combine 4 KV-splits: ctx = sum(O_z) / sum(l_z) ----------------
__global__ __launch_bounds__(256) void k_combine(
    const unsigned short* __restrict__ O0, const unsigned short* __restrict__ O1,
    const unsigned short* __restrict__ O2, const unsigned short* __restrict__ O3,
    const float* __restrict__ lbuf, unsigned short* __restrict__ ctx) {
  const int idx = blockIdx.x * 256 + threadIdx.x;
  const int row = idx >> 6;
  const int c8 = (idx & 63) * 8;
  const int b = row >> 11, n = row & 2047;
  const int hh = c8 >> 6;
  const int bh = b * 8 + hh;
  const float denom = lbuf[bh * N_ + n] + lbuf[(16 + bh) * N_ + n] +
                      lbuf[(32 + bh) * N_ + n] + lbuf[(48 + bh) * N_ + n];
  const float inv = 1.f / denom;
  const int off = row * 512 + c8;
  u32x4 v0 = *reinterpret_cast<const u32x4*>(&O0[off]);
  u32x4 v1 = *reinterpret_cast<const u32x4*>(&O1[off]);
  u32x4 v2 = *reinterpret_cast<const u32x4*>(&O2[off]);
  u32x4 v3 = *reinterpret_cast<const u32x4*>(&O3[off]);
  u32x4 ov;
#pragma unroll
  for (int j = 0; j < 4; ++j) {
    float lo = bf2f((unsigned short)(v0[j] & 0xffff)) + bf2f((unsigned short)(v1[j] & 0xffff)) +
               bf2f((unsigned short)(v2[j] & 0xffff)) + bf2f((unsigned short)(v3[j] & 0xffff));
    float hi = bf2f((unsigned short)(v0[j] >> 16)) + bf2f((unsigned short)(v1[j] >> 16)) +
               bf2f((unsigned short)(v2[j] >> 16)) + bf2f((unsigned short)(v3[j] >> 16));
    ov[j] = pack2(lo * inv, hi * inv);
  }
  *reinterpret_cast<u32x4*>(&ctx[off]) = ov;
}

// ---------------- x = ctxB @ WfT + h ; LayerNorm fused ----------------
// grid 256 blocks of 16 rows; 8 waves, wave w = col-tile w.
__global__ __launch_bounds__(512) void k_final(
    const unsigned short* __restrict__ ctxB, const unsigned short* __restrict__ WfT,
    const float* __restrict__ h, const float* __restrict__ gamma,
    const float* __restrict__ beta, float* __restrict__ out) {
  __shared__ float red[2][16][9];
  __shared__ float mur[16], rsr[16];
  const int tid = threadIdx.x;
  const int w = tid >> 6, lane = tid & 63;
  const int c = lane & 15, g = lane >> 4;
  const int rowbase = blockIdx.x * 16;

  f32x4 acc[4];
#pragma unroll
  for (int i = 0; i < 4; ++i) acc[i] = (f32x4){0.f, 0.f, 0.f, 0.f};

#pragma unroll 4
  for (int kt = 0; kt < 512; kt += 32) {
    short8 a = *reinterpret_cast<const short8*>(&ctxB[(rowbase + c) * 512 + kt + 8 * g]);
#pragma unroll
    for (int ht = 0; ht < 4; ++ht) {
      short8 bv = *reinterpret_cast<const short8*>(
          &WfT[(w * 64 + ht * 16 + c) * 512 + kt + 8 * g]);
      acc[ht] = __builtin_amdgcn_mfma_f32_16x16x32_bf16(a, bv, acc[ht], 0, 0, 0);
    }
  }
  // x = fh + h ; per-row stats
  float x[4][4];
  float px[4], pxx[4];
#pragma unroll
  for (int r = 0; r < 4; ++r) { px[r] = 0.f; pxx[r] = 0.f; }
#pragma unroll
  for (int ht = 0; ht < 4; ++ht)
#pragma unroll
    for (int r = 0; r < 4; ++r) {
      float v = acc[ht][r] + h[(rowbase + 4 * g + r) * 512 + w * 64 + ht * 16 + c];
      x[ht][r] = v;
      px[r] += v;
      pxx[r] += v * v;
    }
#pragma unroll
  for (int msk = 1; msk < 16; msk <<= 1)
#pragma unroll
    for (int r = 0; r < 4; ++r) {
      px[r] += __shfl_xor(px[r], msk);
      pxx[r] += __shfl_xor(pxx[r], msk);
    }
  if (c == 0) {
#pragma unroll
    for (int r = 0; r < 4; ++r) {
      red[0][4 * g + r][w] = px[r];
      red[1][4 * g + r][w] = pxx[r];
    }
  }
  __syncthreads();
  if (tid < 16) {
    float s = 0.f, sq = 0.f;
#pragma unroll
    for (int wv = 0; wv < 8; ++wv) { s += red[0][tid][wv]; sq += red[1][tid][wv]; }
    float mu = s * (1.f / 512.f);
    float var = sq * (1.f / 512.f) - mu * mu;
    mur[tid] = mu;
    rsr[tid] = rsqrtf(var + 1e-5f);
  }
  __syncthreads();
#pragma unroll
  for (int ht = 0; ht < 4; ++ht)
#pragma unroll
    for (int r = 0; r < 4; ++r) {
      const int col = w * 64 + ht * 16 + c;
      const float mu = mur[4 * g + r], rs = rsr[4 * g + r];
      out[(rowbase + 4 * g + r) * 512 + col] =
          (x[ht][r] - mu) * rs * gamma[col] + beta[col];
    }
}

extern "C" void kernel_launch(void* const* d_in, const int* in_sizes, int n_in,
                              void* d_out, int out_size, void* d_ws, size_t ws_size,
                              hipStream_t stream) {
  const float* h     = (const float*)d_in[0];
  const float* rh    = (const float*)d_in[1];
  // d_in[2] = Wl, d_in[4] = al: dead (softmax shift-invariance along j)
  const float* Wr    = (const float*)d_in[3];
  const float* ar    = (const float*)d_in[5];
  const float* Wrs   = (const float*)d_in[6];
  const float* Wrt   = (const float*)d_in[7];
  const float* Wf    = (const float*)d_in[8];
  const float* gamma = (const float*)d_in[9];
  const float* beta  = (const float*)d_in[10];

  const size_t MB = 1ull << 20;
  char* ws = (char*)d_ws;
  unsigned short* frB  = (unsigned short*)(ws);                          // 4 MB (→ ctxB)
  unsigned short* rk   = (unsigned short*)(ws + 4 * MB);                 // 1 MB
  unsigned short* rq   = (unsigned short*)(ws + 5 * MB);                 // 1 MB
  float*          sr   = (float*)(ws + 6 * MB);                          // 128 KB
  float*          lbuf = (float*)(ws + 6 * MB + 256 * 1024);             // 512 KB
  unsigned short* WrT  = (unsigned short*)(ws + 6 * MB + 768 * 1024);    // 512 KB
  unsigned short* WfT  = (unsigned short*)(ws + 7 * MB + 256 * 1024);    // 512 KB
  unsigned short* O0   = (unsigned short*)(ws + 7 * MB + 768 * 1024);    // 4 MB
  unsigned short* O1   = (unsigned short*)(ws + 11 * MB + 768 * 1024);   // 4 MB (15.75 MB)
  unsigned short* O2   = (unsigned short*)d_out;                         // 4 MB (scratch)
  unsigned short* O3   = (unsigned short*)((char*)d_out + 4 * MB);       // 4 MB (scratch)

  hipLaunchKernelGGL(k_cast_wT, dim3(16, 16, 2), dim3(256), 0, stream, Wr, Wf, WrT, WfT);
  hipLaunchKernelGGL(k_projr, dim3(1024), dim3(256), 0, stream, rh, Wrs, Wrt, rk, rq);
  hipLaunchKernelGGL(k_proj_fr, dim3(256, 2), dim3(256), 0, stream, h, WrT, ar, frB, sr);
  hipLaunchKernelGGL(k_attn, dim3(32, 16, 4), dim3(128), 0, stream, rk, rq, sr, frB,
                     O0, O1, O2, O3, lbuf);
  hipLaunchKernelGGL(k_combine, dim3(1024), dim3(256), 0, stream, O0, O1, O2, O3, lbuf, frB);
  hipLaunchKernelGGL(k_final, dim3(256), dim3(512), 0, stream, frB, WfT, h, gamma, beta,
                     (float*)d_out);
}

// Round 8
// 175.723 us; speedup vs baseline: 1.2878x; 1.0575x over previous
//
#include <hip/hip_runtime.h>
#include <hip/hip_bf16.h>

typedef __attribute__((ext_vector_type(8))) short short8;
typedef __attribute__((ext_vector_type(4))) float f32x4;
typedef __attribute__((ext_vector_type(16))) float f32x16;
typedef __attribute__((ext_vector_type(4))) unsigned int u32x4;
typedef __attribute__((ext_vector_type(2))) unsigned int u32x2;
typedef __attribute__((ext_vector_type(2))) int i32x2;

#define N_ 2048

__device__ __forceinline__ unsigned short f2bf(float f) {
  return __builtin_bit_cast(unsigned short, __float2bfloat16(f));
}
__device__ __forceinline__ float bf2f(unsigned short u) {
  return __builtin_bit_cast(float, ((unsigned int)u) << 16);
}
__device__ __forceinline__ unsigned int pack2(float lo, float hi) {
  return ((unsigned int)f2bf(hi) << 16) | (unsigned int)f2bf(lo);
}

// ---------------- prep: transpose-cast Wr/Wf  +  rk/rq projections ----------------
// grid 2560: blocks 0..511 = cast_wT (16x16x2); 512..2559 = projr (2048, 2 rows each)
__global__ __launch_bounds__(256) void k_prep(
    const float* __restrict__ Wr, const float* __restrict__ Wf,
    const float* __restrict__ rh, const float* __restrict__ Wrs,
    const float* __restrict__ Wrt,
    unsigned short* __restrict__ WrT, unsigned short* __restrict__ WfT,
    unsigned short* __restrict__ rk, unsigned short* __restrict__ rq) {
  __shared__ float t[32][33];
  const int bid = blockIdx.x;
  const int tid = threadIdx.x;
  if (bid < 512) {
    const int zz = bid >> 8, rem = bid & 255;
    const int kt = (rem & 15) * 32, ct = (rem >> 4) * 32;
    const float* W = zz ? Wf : Wr;
    unsigned short* WT = zz ? WfT : WrT;
    const int r = tid >> 3, c4 = (tid & 7) * 4;
    f32x4 v = *reinterpret_cast<const f32x4*>(&W[(kt + r) * 512 + ct + c4]);
#pragma unroll
    for (int j = 0; j < 4; ++j) t[r][c4 + j] = v[j];
    __syncthreads();
    u32x2 o;
    o[0] = pack2(t[c4][r], t[c4 + 1][r]);
    o[1] = pack2(t[c4 + 2][r], t[c4 + 3][r]);
    *reinterpret_cast<u32x2*>(&WT[(ct + r) * 512 + kt + c4]) = o;
  } else {
    const int pb = bid - 512;
    const int col = tid & 127;
    const int ro = tid >> 7;
    const int nf = pb * 2 + ro;  // 0..4095
    const f32x4* src = reinterpret_cast<const f32x4*>(&rh[nf * 16]);
    f32x4 rv[4] = {src[0], src[1], src[2], src[3]};
    float sk = 0.f, sq = 0.f;
#pragma unroll
    for (int k4 = 0; k4 < 4; ++k4)
#pragma unroll
      for (int j = 0; j < 4; ++j) {
        float v = rv[k4][j];
        int k = k4 * 4 + j;
        sk += v * Wrs[k * 128 + col];
        sq += v * Wrt[k * 128 + col];
      }
    int bb = nf >> 11, n = nf & 2047, hh = col >> 4, r = col & 15;
    int oidx = ((bb * 8 + hh) * N_ + n) * 16 + r;
    rk[oidx] = f2bf(sk);
    rq[oidx] = f2bf(sq);
  }
}

// ---------------- fr = h @ WrT (MFMA, fused cast); sr; frBt = fr^T A-frag layout ----------------
// grid (256, 2); block 256 = 4 waves; wave w -> head blockIdx.y*4+w; 16 rows/block.
__global__ __launch_bounds__(256) void k_proj_fr(
    const float* __restrict__ h, const unsigned short* __restrict__ WrT,
    const float* __restrict__ ar,
    unsigned short* __restrict__ frBt, float* __restrict__ sr) {
  const int tid = threadIdx.x;
  const int w = tid >> 6, lane = tid & 63;
  const int c = lane & 15, g = lane >> 4;
  const int rowbase = blockIdx.x * 16;
  const int hh = blockIdx.y * 4 + w;

  f32x4 acc[4];
#pragma unroll
  for (int i = 0; i < 4; ++i) acc[i] = (f32x4){0.f, 0.f, 0.f, 0.f};

#pragma unroll 4
  for (int kt = 0; kt < 512; kt += 32) {
    const float* hp = &h[(rowbase + c) * 512 + kt + 8 * g];
    f32x4 h0 = *reinterpret_cast<const f32x4*>(hp);
    f32x4 h1 = *reinterpret_cast<const f32x4*>(hp + 4);
    u32x4 aw;
    aw[0] = pack2(h0[0], h0[1]);
    aw[1] = pack2(h0[2], h0[3]);
    aw[2] = pack2(h1[0], h1[1]);
    aw[3] = pack2(h1[2], h1[3]);
    short8 a = __builtin_bit_cast(short8, aw);
#pragma unroll
    for (int ht = 0; ht < 4; ++ht) {
      short8 bv = *reinterpret_cast<const short8*>(
          &WrT[(hh * 64 + ht * 16 + c) * 512 + kt + 8 * g]);
      acc[ht] = __builtin_amdgcn_mfma_f32_16x16x32_bf16(a, bv, acc[ht], 0, 0, 0);
    }
  }

  const int b = rowbase >> 11;
  const int bh = b * 8 + hh;
  const int nloc = rowbase & 2047;
  const int jb = nloc >> 4;  // 16-row block index

  float arv[4];
#pragma unroll
  for (int ht = 0; ht < 4; ++ht) arv[ht] = ar[ht * 16 + c];

  float ps[4];
#pragma unroll
  for (int r = 0; r < 4; ++r) {
    float s = 0.f;
#pragma unroll
    for (int ht = 0; ht < 4; ++ht) {
      float v = acc[ht][r];
      float lv = v >= 0.f ? v : 0.01f * v;
      s += lv * arv[ht];
    }
    ps[r] = s;
  }
#pragma unroll
  for (int msk = 1; msk < 16; msk <<= 1)
#pragma unroll
    for (int r = 0; r < 4; ++r) ps[r] += __shfl_xor(ps[r], msk);
  if (c == 0) {
#pragma unroll
    for (int r = 0; r < 4; ++r) sr[bh * N_ + nloc + 4 * g + r] = ps[r];
  }
  // frBt[bh][jb(128)][hd(64)][jloc(16)] bf16: A-fragment layout for PV (fr^T)
#pragma unroll
  for (int ht = 0; ht < 4; ++ht) {
    int hd = ht * 16 + c;
    u32x2 ov;
    ov[0] = pack2(acc[ht][0], acc[ht][1]);
    ov[1] = pack2(acc[ht][2], acc[ht][3]);
    *reinterpret_cast<u32x2*>(
        &frBt[(((size_t)bh * 128 + jb) * 64 + hd) * 16 + 4 * g]) = ov;
  }
}

// ---------------- flash attention, 32x32x16 MFMA, m=0 exact softmax, KV-split x4 ----------------
// grid (64, 16, 4); block 64 = 1 wave; 32 q-rows x 512 j per wave; NO LDS, no branches.
__global__ __launch_bounds__(64) void k_attn(
    const unsigned short* __restrict__ rk, const unsigned short* __restrict__ rq,
    const float* __restrict__ sr, const unsigned short* __restrict__ frBt,
    unsigned short* __restrict__ O0, unsigned short* __restrict__ O1,
    unsigned short* __restrict__ O2, unsigned short* __restrict__ O3,
    float* __restrict__ lbuf) {
  const int lane = threadIdx.x;
  const int c5 = lane & 31, hi = lane >> 5;
  const int bh = blockIdx.y, b = bh >> 3, hh = bh & 7;
  const int z = blockIdx.z;
  const int qbase = blockIdx.x * 32;

  // B-fragment: rk rows for the 32 queries (col = lane&31, k = 8*hi+e)
  const short8 brk =
      *reinterpret_cast<const short8*>(&rk[(bh * N_ + qbase + c5) * 16 + 8 * hi]);

  f32x16 Oa = {0.f, 0.f, 0.f, 0.f, 0.f, 0.f, 0.f, 0.f,
               0.f, 0.f, 0.f, 0.f, 0.f, 0.f, 0.f, 0.f};
  f32x16 Ob = Oa;
  float l = 0.f;
  const float* sr_bh = sr + bh * N_;
  const unsigned short* rq_bh = rq + (size_t)bh * N_ * 16;
  const unsigned short* fb = frBt + (size_t)bh * 128 * 64 * 16;

  for (int it = 0; it < 4; ++it) {
    const int j0 = z * 512 + it * 128;
#pragma unroll
    for (int t = 0; t < 4; ++t) {
      const int jb = j0 + t * 32;
      // QK: S^T[j(32) x q(32)], K=16 exact
      short8 a = *reinterpret_cast<const short8*>(&rq_bh[(jb + c5) * 16 + 8 * hi]);
      f32x16 zz = {0.f, 0.f, 0.f, 0.f, 0.f, 0.f, 0.f, 0.f,
                   0.f, 0.f, 0.f, 0.f, 0.f, 0.f, 0.f, 0.f};
      f32x16 S = __builtin_amdgcn_mfma_f32_32x32x16_bf16(a, brk, zz, 0, 0, 0);
      // + sr[j] (row-uniform per half-wave): C/D row j = (r&3)+8*(r>>2)+4*hi
      f32x4 sa = *reinterpret_cast<const f32x4*>(&sr_bh[jb + 4 * hi]);
      f32x4 sb = *reinterpret_cast<const f32x4*>(&sr_bh[jb + 8 + 4 * hi]);
      f32x4 sc = *reinterpret_cast<const f32x4*>(&sr_bh[jb + 16 + 4 * hi]);
      f32x4 sd = *reinterpret_cast<const f32x4*>(&sr_bh[jb + 24 + 4 * hi]);
      float p[16];
#pragma unroll
      for (int r = 0; r < 4; ++r) p[r] = __expf(S[r] + sa[r]);
#pragma unroll
      for (int r = 0; r < 4; ++r) p[4 + r] = __expf(S[4 + r] + sb[r]);
#pragma unroll
      for (int r = 0; r < 4; ++r) p[8 + r] = __expf(S[8 + r] + sc[r]);
#pragma unroll
      for (int r = 0; r < 4; ++r) p[12 + r] = __expf(S[12 + r] + sd[r]);
#pragma unroll
      for (int r = 0; r < 16; ++r) l += p[r];
      // pack P (f32, C/D layout) -> PV B-fragments via permlane32_swap
      int A1 = (int)pack2(p[0], p[1]), B1 = (int)pack2(p[2], p[3]);
      int C1 = (int)pack2(p[4], p[5]), D1 = (int)pack2(p[6], p[7]);
      i32x2 r0 = __builtin_amdgcn_permlane32_swap(A1, C1, false, false);
      i32x2 r1 = __builtin_amdgcn_permlane32_swap(B1, D1, false, false);
      int A2 = (int)pack2(p[8], p[9]), B2 = (int)pack2(p[10], p[11]);
      int C2 = (int)pack2(p[12], p[13]), D2 = (int)pack2(p[14], p[15]);
      i32x2 r2 = __builtin_amdgcn_permlane32_swap(A2, C2, false, false);
      i32x2 r3 = __builtin_amdgcn_permlane32_swap(B2, D2, false, false);
      u32x4 f1, f2;
      f1[0] = (unsigned)r0[0]; f1[1] = (unsigned)r1[0];
      f1[2] = (unsigned)r0[1]; f1[3] = (unsigned)r1[1];
      f2[0] = (unsigned)r2[0]; f2[1] = (unsigned)r3[0];
      f2[2] = (unsigned)r2[1]; f2[3] = (unsigned)r3[1];
      short8 pb1 = __builtin_bit_cast(short8, f1);
      short8 pb2 = __builtin_bit_cast(short8, f2);
      // PV: O^T[hd x q] += fr^T[hd x j] * P^T[j x q], two k-halves x two hd-tiles
      const unsigned short* fp0 = fb + ((size_t)(jb >> 4) * 64) * 16 + 8 * hi;
      const unsigned short* fp1 = fp0 + 64 * 16;
      short8 av;
      av = *reinterpret_cast<const short8*>(fp0 + c5 * 16);
      Oa = __builtin_amdgcn_mfma_f32_32x32x16_bf16(av, pb1, Oa, 0, 0, 0);
      av = *reinterpret_cast<const short8*>(fp0 + (32 + c5) * 16);
      Ob = __builtin_amdgcn_mfma_f32_32x32x16_bf16(av, pb1, Ob, 0, 0, 0);
      av = *reinterpret_cast<const short8*>(fp1 + c5 * 16);
      Oa = __builtin_amdgcn_mfma_f32_32x32x16_bf16(av, pb2, Oa, 0, 0, 0);
      av = *reinterpret_cast<const short8*>(fp1 + (32 + c5) * 16);
      Ob = __builtin_amdgcn_mfma_f32_32x32x16_bf16(av, pb2, Ob, 0, 0, 0);
    }
  }
  // epilogue
  l += __shfl_xor(l, 32);
  if (hi == 0) lbuf[(z * 16 + bh) * N_ + qbase + c5] = l;
  unsigned short* Oz = (z == 0) ? O0 : (z == 1) ? O1 : (z == 2) ? O2 : O3;
  unsigned int* orow = reinterpret_cast<unsigned int*>(
      &Oz[((size_t)(b * N_ + qbase + c5)) * 512 + hh * 64]);
#pragma unroll
  for (int r = 0; r < 16; r += 2) {
    const int hd = (r & 3) + 8 * (r >> 2) + 4 * hi;
    orow[hd >> 1] = pack2(Oa[r], Oa[r + 1]);
    orow[(32 + hd) >> 1] = pack2(Ob[r], Ob[r + 1]);
  }
}

// ---------------- combine 4 KV-splits: ctx = sum(O_z) / sum(l_z) ----------------
__global__ __launch_bounds__(256) void k_combine(
    const unsigned short* __restrict__ O0, const unsigned short* __restrict__ O1,
    const unsigned short* __restrict__ O2, const unsigned short* __restrict__ O3,
    const float* __restrict__ lbuf, unsigned short* __restrict__ ctx) {
  const int idx = blockIdx.x * 256 + threadIdx.x;
  const int row = idx >> 6;
  const int c8 = (idx & 63) * 8;
  const int b = row >> 11, n = row & 2047;
  const int hh = c8 >> 6;
  const int bh = b * 8 + hh;
  const float denom = lbuf[bh * N_ + n] + lbuf[(16 + bh) * N_ + n] +
                      lbuf[(32 + bh) * N_ + n] + lbuf[(48 + bh) * N_ + n];
  const float inv = 1.f / denom;
  const int off = row * 512 + c8;
  u32x4 v0 = *reinterpret_cast<const u32x4*>(&O0[off]);
  u32x4 v1 = *reinterpret_cast<const u32x4*>(&O1[off]);
  u32x4 v2 = *reinterpret_cast<const u32x4*>(&O2[off]);
  u32x4 v3 = *reinterpret_cast<const u32x4*>(&O3[off]);
  u32x4 ov;
#pragma unroll
  for (int j = 0; j < 4; ++j) {
    float lo = bf2f((unsigned short)(v0[j] & 0xffff)) + bf2f((unsigned short)(v1[j] & 0xffff)) +
               bf2f((unsigned short)(v2[j] & 0xffff)) + bf2f((unsigned short)(v3[j] & 0xffff));
    float hi = bf2f((unsigned short)(v0[j] >> 16)) + bf2f((unsigned short)(v1[j] >> 16)) +
               bf2f((unsigned short)(v2[j] >> 16)) + bf2f((unsigned short)(v3[j] >> 16));
    ov[j] = pack2(lo * inv, hi * inv);
  }
  *reinterpret_cast<u32x4*>(&ctx[off]) = ov;
}

// ---------------- x = ctxB @ WfT + h ; LayerNorm fused ----------------
// grid 256 blocks of 16 rows; 8 waves, wave w = col-tile w.
__global__ __launch_bounds__(512) void k_final(
    const unsigned short* __restrict__ ctxB, const unsigned short* __restrict__ WfT,
    const float* __restrict__ h, const float* __restrict__ gamma,
    const float* __restrict__ beta, float* __restrict__ out) {
  __shared__ float red[2][16][9];
  __shared__ float mur[16], rsr[16];
  const int tid = threadIdx.x;
  const int w = tid >> 6, lane = tid & 63;
  const int c = lane & 15, g = lane >> 4;
  const int rowbase = blockIdx.x * 16;

  f32x4 acc[4];
#pragma unroll
  for (int i = 0; i < 4; ++i) acc[i] = (f32x4){0.f, 0.f, 0.f, 0.f};

#pragma unroll 4
  for (int kt = 0; kt < 512; kt += 32) {
    short8 a = *reinterpret_cast<const short8*>(&ctxB[(rowbase + c) * 512 + kt + 8 * g]);
#pragma unroll
    for (int ht = 0; ht < 4; ++ht) {
      short8 bv = *reinterpret_cast<const short8*>(
          &WfT[(w * 64 + ht * 16 + c) * 512 + kt + 8 * g]);
      acc[ht] = __builtin_amdgcn_mfma_f32_16x16x32_bf16(a, bv, acc[ht], 0, 0, 0);
    }
  }
  // x = fh + h ; per-row stats
  float x[4][4];
  float px[4], pxx[4];
#pragma unroll
  for (int r = 0; r < 4; ++r) { px[r] = 0.f; pxx[r] = 0.f; }
#pragma unroll
  for (int ht = 0; ht < 4; ++ht)
#pragma unroll
    for (int r = 0; r < 4; ++r) {
      float v = acc[ht][r] + h[(rowbase + 4 * g + r) * 512 + w * 64 + ht * 16 + c];
      x[ht][r] = v;
      px[r] += v;
      pxx[r] += v * v;
    }
#pragma unroll
  for (int msk = 1; msk < 16; msk <<= 1)
#pragma unroll
    for (int r = 0; r < 4; ++r) {
      px[r] += __shfl_xor(px[r], msk);
      pxx[r] += __shfl_xor(pxx[r], msk);
    }
  if (c == 0) {
#pragma unroll
    for (int r = 0; r < 4; ++r) {
      red[0][4 * g + r][w] = px[r];
      red[1][4 * g + r][w] = pxx[r];
    }
  }
  __syncthreads();
  if (tid < 16) {
    float s = 0.f, sq = 0.f;
#pragma unroll
    for (int wv = 0; wv < 8; ++wv) { s += red[0][tid][wv]; sq += red[1][tid][wv]; }
    float mu = s * (1.f / 512.f);
    float var = sq * (1.f / 512.f) - mu * mu;
    mur[tid] = mu;
    rsr[tid] = rsqrtf(var + 1e-5f);
  }
  __syncthreads();
#pragma unroll
  for (int ht = 0; ht < 4; ++ht)
#pragma unroll
    for (int r = 0; r < 4; ++r) {
      const int col = w * 64 + ht * 16 + c;
      const float mu = mur[4 * g + r], rs = rsr[4 * g + r];
      out[(rowbase + 4 * g + r) * 512 + col] =
          (x[ht][r] - mu) * rs * gamma[col] + beta[col];
    }
}

extern "C" void kernel_launch(void* const* d_in, const int* in_sizes, int n_in,
                              void* d_out, int out_size, void* d_ws, size_t ws_size,
                              hipStream_t stream) {
  const float* h     = (const float*)d_in[0];
  const float* rh    = (const float*)d_in[1];
  // d_in[2] = Wl, d_in[4] = al: dead (softmax shift-invariance along j)
  const float* Wr    = (const float*)d_in[3];
  const float* ar    = (const float*)d_in[5];
  const float* Wrs   = (const float*)d_in[6];
  const float* Wrt   = (const float*)d_in[7];
  const float* Wf    = (const float*)d_in[8];
  const float* gamma = (const float*)d_in[9];
  const float* beta  = (const float*)d_in[10];

  const size_t MB = 1ull << 20;
  char* ws = (char*)d_ws;
  unsigned short* frBt = (unsigned short*)(ws);                          // 4 MB (→ ctxB)
  unsigned short* rk   = (unsigned short*)(ws + 4 * MB);                 // 1 MB
  unsigned short* rq   = (unsigned short*)(ws + 5 * MB);                 // 1 MB
  float*          sr   = (float*)(ws + 6 * MB);                          // 128 KB
  float*          lbuf = (float*)(ws + 6 * MB + 256 * 1024);             // 512 KB
  unsigned short* WrT  = (unsigned short*)(ws + 6 * MB + 768 * 1024);    // 512 KB
  unsigned short* WfT  = (unsigned short*)(ws + 7 * MB + 256 * 1024);    // 512 KB
  unsigned short* O0   = (unsigned short*)(ws + 7 * MB + 768 * 1024);    // 4 MB
  unsigned short* O1   = (unsigned short*)(ws + 11 * MB + 768 * 1024);   // 4 MB (15.75 MB)
  unsigned short* O2   = (unsigned short*)d_out;                         // 4 MB (scratch)
  unsigned short* O3   = (unsigned short*)((char*)d_out + 4 * MB);       // 4 MB (scratch)

  hipLaunchKernelGGL(k_prep, dim3(2560), dim3(256), 0, stream,
                     Wr, Wf, rh, Wrs, Wrt, WrT, WfT, rk, rq);
  hipLaunchKernelGGL(k_proj_fr, dim3(256, 2), dim3(256), 0, stream, h, WrT, ar, frBt, sr);
  hipLaunchKernelGGL(k_attn, dim3(64, 16, 4), dim3(64), 0, stream, rk, rq, sr, frBt,
                     O0, O1, O2, O3, lbuf);
  hipLaunchKernelGGL(k_combine, dim3(1024), dim3(256), 0, stream, O0, O1, O2, O3, lbuf, frBt);
  hipLaunchKernelGGL(k_final, dim3(256), dim3(512), 0, stream, frBt, WfT, h, gamma, beta,
                     (float*)d_out);
}

// Round 9
// 164.998 us; speedup vs baseline: 1.3715x; 1.0650x over previous
//
#include <hip/hip_runtime.h>
#include <hip/hip_bf16.h>

typedef __attribute__((ext_vector_type(8))) short short8;
typedef __attribute__((ext_vector_type(4))) float f32x4;
typedef __attribute__((ext_vector_type(16))) float f32x16;
typedef __attribute__((ext_vector_type(4))) unsigned int u32x4;
typedef __attribute__((ext_vector_type(2))) unsigned int u32x2;
typedef __attribute__((ext_vector_type(2))) int i32x2;

#define N_ 2048

__device__ __forceinline__ unsigned short f2bf(float f) {
  return __builtin_bit_cast(unsigned short, __float2bfloat16(f));
}
__device__ __forceinline__ float bf2f(unsigned short u) {
  return __builtin_bit_cast(float, ((unsigned int)u) << 16);
}
__device__ __forceinline__ unsigned int pack2(float lo, float hi) {
  return ((unsigned int)f2bf(hi) << 16) | (unsigned int)f2bf(lo);
}

// ---------------- prep: transpose-cast Wr/Wf  +  rk/rq projections ----------------
// grid 2560: blocks 0..511 = cast_wT (16x16x2); 512..2559 = projr (2048, 2 rows each)
__global__ __launch_bounds__(256) void k_prep(
    const float* __restrict__ Wr, const float* __restrict__ Wf,
    const float* __restrict__ rh, const float* __restrict__ Wrs,
    const float* __restrict__ Wrt,
    unsigned short* __restrict__ WrT, unsigned short* __restrict__ WfT,
    unsigned short* __restrict__ rk, unsigned short* __restrict__ rq) {
  __shared__ float t[32][33];
  const int bid = blockIdx.x;
  const int tid = threadIdx.x;
  if (bid < 512) {
    const int zz = bid >> 8, rem = bid & 255;
    const int kt = (rem & 15) * 32, ct = (rem >> 4) * 32;
    const float* W = zz ? Wf : Wr;
    unsigned short* WT = zz ? WfT : WrT;
    const int r = tid >> 3, c4 = (tid & 7) * 4;
    f32x4 v = *reinterpret_cast<const f32x4*>(&W[(kt + r) * 512 + ct + c4]);
#pragma unroll
    for (int j = 0; j < 4; ++j) t[r][c4 + j] = v[j];
    __syncthreads();
    u32x2 o;
    o[0] = pack2(t[c4][r], t[c4 + 1][r]);
    o[1] = pack2(t[c4 + 2][r], t[c4 + 3][r]);
    *reinterpret_cast<u32x2*>(&WT[(ct + r) * 512 + kt + c4]) = o;
  } else {
    const int pb = bid - 512;
    const int col = tid & 127;
    const int ro = tid >> 7;
    const int nf = pb * 2 + ro;  // 0..4095
    const f32x4* src = reinterpret_cast<const f32x4*>(&rh[nf * 16]);
    f32x4 rv[4] = {src[0], src[1], src[2], src[3]};
    float sk = 0.f, sq = 0.f;
#pragma unroll
    for (int k4 = 0; k4 < 4; ++k4)
#pragma unroll
      for (int j = 0; j < 4; ++j) {
        float v = rv[k4][j];
        int k = k4 * 4 + j;
        sk += v * Wrs[k * 128 + col];
        sq += v * Wrt[k * 128 + col];
      }
    int bb = nf >> 11, n = nf & 2047, hh = col >> 4, r = col & 15;
    int oidx = ((bb * 8 + hh) * N_ + n) * 16 + r;
    rk[oidx] = f2bf(sk);
    rq[oidx] = f2bf(sq);
  }
}

// ---------------- fr = h @ WrT (MFMA, fused cast); sr; frBt = fr^T A-frag layout ----------------
// grid (256, 2); block 256 = 4 waves; wave w -> head blockIdx.y*4+w; 16 rows/block.
__global__ __launch_bounds__(256) void k_proj_fr(
    const float* __restrict__ h, const unsigned short* __restrict__ WrT,
    const float* __restrict__ ar,
    unsigned short* __restrict__ frBt, float* __restrict__ sr) {
  const int tid = threadIdx.x;
  const int w = tid >> 6, lane = tid & 63;
  const int c = lane & 15, g = lane >> 4;
  const int rowbase = blockIdx.x * 16;
  const int hh = blockIdx.y * 4 + w;

  f32x4 acc[4];
#pragma unroll
  for (int i = 0; i < 4; ++i) acc[i] = (f32x4){0.f, 0.f, 0.f, 0.f};

#pragma unroll 4
  for (int kt = 0; kt < 512; kt += 32) {
    const float* hp = &h[(rowbase + c) * 512 + kt + 8 * g];
    f32x4 h0 = *reinterpret_cast<const f32x4*>(hp);
    f32x4 h1 = *reinterpret_cast<const f32x4*>(hp + 4);
    u32x4 aw;
    aw[0] = pack2(h0[0], h0[1]);
    aw[1] = pack2(h0[2], h0[3]);
    aw[2] = pack2(h1[0], h1[1]);
    aw[3] = pack2(h1[2], h1[3]);
    short8 a = __builtin_bit_cast(short8, aw);
#pragma unroll
    for (int ht = 0; ht < 4; ++ht) {
      short8 bv = *reinterpret_cast<const short8*>(
          &WrT[(hh * 64 + ht * 16 + c) * 512 + kt + 8 * g]);
      acc[ht] = __builtin_amdgcn_mfma_f32_16x16x32_bf16(a, bv, acc[ht], 0, 0, 0);
    }
  }

  const int b = rowbase >> 11;
  const int bh = b * 8 + hh;
  const int nloc = rowbase & 2047;
  const int jb = nloc >> 4;  // 16-row block index

  float arv[4];
#pragma unroll
  for (int ht = 0; ht < 4; ++ht) arv[ht] = ar[ht * 16 + c];

  float ps[4];
#pragma unroll
  for (int r = 0; r < 4; ++r) {
    float s = 0.f;
#pragma unroll
    for (int ht = 0; ht < 4; ++ht) {
      float v = acc[ht][r];
      float lv = v >= 0.f ? v : 0.01f * v;
      s += lv * arv[ht];
    }
    ps[r] = s;
  }
#pragma unroll
  for (int msk = 1; msk < 16; msk <<= 1)
#pragma unroll
    for (int r = 0; r < 4; ++r) ps[r] += __shfl_xor(ps[r], msk);
  if (c == 0) {
#pragma unroll
    for (int r = 0; r < 4; ++r) sr[bh * N_ + nloc + 4 * g + r] = ps[r];
  }
  // frBt[bh][jb(128)][hd(64)][jloc(16)] bf16: A-fragment layout for PV (fr^T)
#pragma unroll
  for (int ht = 0; ht < 4; ++ht) {
    int hd = ht * 16 + c;
    u32x2 ov;
    ov[0] = pack2(acc[ht][0], acc[ht][1]);
    ov[1] = pack2(acc[ht][2], acc[ht][3]);
    *reinterpret_cast<u32x2*>(
        &frBt[(((size_t)bh * 128 + jb) * 64 + hd) * 16 + 4 * g]) = ov;
  }
}

// ---------------- flash attention: LDS-staged fr, 32x32x16 MFMA, m=0 softmax, KV-split x4 ----
// grid (8, 16, 4); block 512 = 8 waves; each block = one (bh, z), stages 64KB fr quarter.
__global__ __launch_bounds__(512) void k_attn(
    const unsigned short* __restrict__ rk, const unsigned short* __restrict__ rq,
    const float* __restrict__ sr, const unsigned short* __restrict__ frBt,
    unsigned short* __restrict__ O0, unsigned short* __restrict__ O1,
    unsigned short* __restrict__ O2, unsigned short* __restrict__ O3,
    float* __restrict__ lbuf) {
  __shared__ unsigned short fr_lds[32 * 64 * 16];  // 64 KB: [jb16_loc][hd][j16]
  const int tid = threadIdx.x;
  const int wave = tid >> 6, lane = tid & 63;
  const int c5 = lane & 31, hi = lane >> 5;
  const int bh = blockIdx.y, b = bh >> 3, hh = bh & 7;
  const int z = blockIdx.z;
  const int qbase = blockIdx.x * 256 + wave * 32;

  // ---- stage fr z-quarter: 32768 elems, 4096 16B-vectors, 8 per thread
  {
    const u32x4* src = reinterpret_cast<const u32x4*>(
        frBt + (((size_t)bh * 128 + z * 32) * 64) * 16);
    u32x4* dst = reinterpret_cast<u32x4*>(fr_lds);
#pragma unroll
    for (int i = 0; i < 8; ++i) dst[tid + i * 512] = src[tid + i * 512];
  }

  // B-fragment: rk rows for this wave's 32 queries
  const short8 brk =
      *reinterpret_cast<const short8*>(&rk[(bh * N_ + qbase + c5) * 16 + 8 * hi]);

  f32x16 Oa = {0.f, 0.f, 0.f, 0.f, 0.f, 0.f, 0.f, 0.f,
               0.f, 0.f, 0.f, 0.f, 0.f, 0.f, 0.f, 0.f};
  f32x16 Ob = Oa;
  float l = 0.f;
  const float* sr_bh = sr + bh * N_;
  const unsigned short* rq_bh = rq + (size_t)bh * N_ * 16;

  __syncthreads();

  for (int it = 0; it < 4; ++it) {
#pragma unroll
    for (int t = 0; t < 4; ++t) {
      const int jl = it * 128 + t * 32;     // j local to the z-quarter
      const int jg = z * 512 + jl;          // global j
      // QK: S^T[j(32) x q(32)], K=16 exact
      short8 a = *reinterpret_cast<const short8*>(&rq_bh[(jg + c5) * 16 + 8 * hi]);
      f32x16 zz = {0.f, 0.f, 0.f, 0.f, 0.f, 0.f, 0.f, 0.f,
                   0.f, 0.f, 0.f, 0.f, 0.f, 0.f, 0.f, 0.f};
      f32x16 S = __builtin_amdgcn_mfma_f32_32x32x16_bf16(a, brk, zz, 0, 0, 0);
      // + sr[j] (row-uniform per half-wave): C/D row j = (r&3)+8*(r>>2)+4*hi
      f32x4 sa = *reinterpret_cast<const f32x4*>(&sr_bh[jg + 4 * hi]);
      f32x4 sb = *reinterpret_cast<const f32x4*>(&sr_bh[jg + 8 + 4 * hi]);
      f32x4 sc = *reinterpret_cast<const f32x4*>(&sr_bh[jg + 16 + 4 * hi]);
      f32x4 sd = *reinterpret_cast<const f32x4*>(&sr_bh[jg + 24 + 4 * hi]);
      float p[16];
#pragma unroll
      for (int r = 0; r < 4; ++r) p[r] = __expf(S[r] + sa[r]);
#pragma unroll
      for (int r = 0; r < 4; ++r) p[4 + r] = __expf(S[4 + r] + sb[r]);
#pragma unroll
      for (int r = 0; r < 4; ++r) p[8 + r] = __expf(S[8 + r] + sc[r]);
#pragma unroll
      for (int r = 0; r < 4; ++r) p[12 + r] = __expf(S[12 + r] + sd[r]);
#pragma unroll
      for (int r = 0; r < 16; ++r) l += p[r];
      // pack P (C/D layout) -> PV B-fragments via permlane32_swap
      int A1 = (int)pack2(p[0], p[1]), B1 = (int)pack2(p[2], p[3]);
      int C1 = (int)pack2(p[4], p[5]), D1 = (int)pack2(p[6], p[7]);
      i32x2 r0 = __builtin_amdgcn_permlane32_swap(A1, C1, false, false);
      i32x2 r1 = __builtin_amdgcn_permlane32_swap(B1, D1, false, false);
      int A2 = (int)pack2(p[8], p[9]), B2 = (int)pack2(p[10], p[11]);
      int C2 = (int)pack2(p[12], p[13]), D2 = (int)pack2(p[14], p[15]);
      i32x2 r2 = __builtin_amdgcn_permlane32_swap(A2, C2, false, false);
      i32x2 r3 = __builtin_amdgcn_permlane32_swap(B2, D2, false, false);
      u32x4 f1, f2;
      f1[0] = (unsigned)r0[0]; f1[1] = (unsigned)r1[0];
      f1[2] = (unsigned)r0[1]; f1[3] = (unsigned)r1[1];
      f2[0] = (unsigned)r2[0]; f2[1] = (unsigned)r3[0];
      f2[2] = (unsigned)r2[1]; f2[3] = (unsigned)r3[1];
      short8 pb1 = __builtin_bit_cast(short8, f1);
      short8 pb2 = __builtin_bit_cast(short8, f2);
      // PV from LDS: O^T[hd x q] += fr^T[hd x j] * P^T[j x q]
      const unsigned short* fp0 = fr_lds + ((jl >> 4) * 64) * 16 + 8 * hi;
      const unsigned short* fp1 = fp0 + 64 * 16;
      short8 av;
      av = *reinterpret_cast<const short8*>(fp0 + c5 * 16);
      Oa = __builtin_amdgcn_mfma_f32_32x32x16_bf16(av, pb1, Oa, 0, 0, 0);
      av = *reinterpret_cast<const short8*>(fp0 + (32 + c5) * 16);
      Ob = __builtin_amdgcn_mfma_f32_32x32x16_bf16(av, pb1, Ob, 0, 0, 0);
      av = *reinterpret_cast<const short8*>(fp1 + c5 * 16);
      Oa = __builtin_amdgcn_mfma_f32_32x32x16_bf16(av, pb2, Oa, 0, 0, 0);
      av = *reinterpret_cast<const short8*>(fp1 + (32 + c5) * 16);
      Ob = __builtin_amdgcn_mfma_f32_32x32x16_bf16(av, pb2, Ob, 0, 0, 0);
    }
  }
  // epilogue
  l += __shfl_xor(l, 32);
  if (hi == 0) lbuf[(z * 16 + bh) * N_ + qbase + c5] = l;
  unsigned short* Oz = (z == 0) ? O0 : (z == 1) ? O1 : (z == 2) ? O2 : O3;
  unsigned int* orow = reinterpret_cast<unsigned int*>(
      &Oz[((size_t)(b * N_ + qbase + c5)) * 512 + hh * 64]);
#pragma unroll
  for (int r = 0; r < 16; r += 2) {
    const int hd = (r & 3) + 8 * (r >> 2) + 4 * hi;
    orow[hd >> 1] = pack2(Oa[r], Oa[r + 1]);
    orow[(32 + hd) >> 1] = pack2(Ob[r], Ob[r + 1]);
  }
}

// ---------------- fused: combine 4 KV-splits + x = ctx @ WfT + h + LayerNorm ----------------
// grid 256 blocks of 16 rows; 8 waves, wave w = col-tile w.
__global__ __launch_bounds__(512) void k_final(
    const unsigned short* __restrict__ O0, const unsigned short* __restrict__ O1,
    const unsigned short* __restrict__ O2, const unsigned short* __restrict__ O3,
    const float* __restrict__ lbuf, const unsigned short* __restrict__ WfT,
    const float* __restrict__ h, const float* __restrict__ gamma,
    const float* __restrict__ beta, float* __restrict__ out) {
  __shared__ unsigned short ctx_lds[16][520];  // row stride 1040B (65x16B)
  __shared__ float red[2][16][9];
  __shared__ float mur[16], rsr[16];
  const int tid = threadIdx.x;
  const int w = tid >> 6, lane = tid & 63;
  const int c = lane & 15, g = lane >> 4;
  const int rowbase = blockIdx.x * 16;

  // ---- combine O0..O3 into ctx_lds (bf16)
  {
    const int row = tid >> 5;            // 0..15
    const int b = (rowbase + row) >> 11, n = (rowbase + row) & 2047;
#pragma unroll
    for (int i = 0; i < 2; ++i) {
      const int col = ((tid & 31) + i * 32) * 8;  // 0..504
      const int bh = b * 8 + (col >> 6);
      const float denom = lbuf[bh * N_ + n] + lbuf[(16 + bh) * N_ + n] +
                          lbuf[(32 + bh) * N_ + n] + lbuf[(48 + bh) * N_ + n];
      const float inv = 1.f / denom;
      const size_t off = (size_t)(rowbase + row) * 512 + col;
      u32x4 v0 = *reinterpret_cast<const u32x4*>(&O0[off]);
      u32x4 v1 = *reinterpret_cast<const u32x4*>(&O1[off]);
      u32x4 v2 = *reinterpret_cast<const u32x4*>(&O2[off]);
      u32x4 v3 = *reinterpret_cast<const u32x4*>(&O3[off]);
      u32x4 ov;
#pragma unroll
      for (int j = 0; j < 4; ++j) {
        float lo = bf2f((unsigned short)(v0[j] & 0xffff)) + bf2f((unsigned short)(v1[j] & 0xffff)) +
                   bf2f((unsigned short)(v2[j] & 0xffff)) + bf2f((unsigned short)(v3[j] & 0xffff));
        float hi = bf2f((unsigned short)(v0[j] >> 16)) + bf2f((unsigned short)(v1[j] >> 16)) +
                   bf2f((unsigned short)(v2[j] >> 16)) + bf2f((unsigned short)(v3[j] >> 16));
        ov[j] = pack2(lo * inv, hi * inv);
      }
      *reinterpret_cast<u32x4*>(&ctx_lds[row][col]) = ov;
    }
  }
  __syncthreads();

  f32x4 acc[4];
#pragma unroll
  for (int i = 0; i < 4; ++i) acc[i] = (f32x4){0.f, 0.f, 0.f, 0.f};

#pragma unroll 4
  for (int kt = 0; kt < 512; kt += 32) {
    short8 a = *reinterpret_cast<const short8*>(&ctx_lds[c][kt + 8 * g]);
#pragma unroll
    for (int ht = 0; ht < 4; ++ht) {
      short8 bv = *reinterpret_cast<const short8*>(
          &WfT[(w * 64 + ht * 16 + c) * 512 + kt + 8 * g]);
      acc[ht] = __builtin_amdgcn_mfma_f32_16x16x32_bf16(a, bv, acc[ht], 0, 0, 0);
    }
  }
  // x = fh + h ; per-row stats
  float x[4][4];
  float px[4], pxx[4];
#pragma unroll
  for (int r = 0; r < 4; ++r) { px[r] = 0.f; pxx[r] = 0.f; }
#pragma unroll
  for (int ht = 0; ht < 4; ++ht)
#pragma unroll
    for (int r = 0; r < 4; ++r) {
      float v = acc[ht][r] + h[(rowbase + 4 * g + r) * 512 + w * 64 + ht * 16 + c];
      x[ht][r] = v;
      px[r] += v;
      pxx[r] += v * v;
    }
#pragma unroll
  for (int msk = 1; msk < 16; msk <<= 1)
#pragma unroll
    for (int r = 0; r < 4; ++r) {
      px[r] += __shfl_xor(px[r], msk);
      pxx[r] += __shfl_xor(pxx[r], msk);
    }
  if (c == 0) {
#pragma unroll
    for (int r = 0; r < 4; ++r) {
      red[0][4 * g + r][w] = px[r];
      red[1][4 * g + r][w] = pxx[r];
    }
  }
  __syncthreads();
  if (tid < 16) {
    float s = 0.f, sq = 0.f;
#pragma unroll
    for (int wv = 0; wv < 8; ++wv) { s += red[0][tid][wv]; sq += red[1][tid][wv]; }
    float mu = s * (1.f / 512.f);
    float var = sq * (1.f / 512.f) - mu * mu;
    mur[tid] = mu;
    rsr[tid] = rsqrtf(var + 1e-5f);
  }
  __syncthreads();
#pragma unroll
  for (int ht = 0; ht < 4; ++ht)
#pragma unroll
    for (int r = 0; r < 4; ++r) {
      const int col = w * 64 + ht * 16 + c;
      const float mu = mur[4 * g + r], rs = rsr[4 * g + r];
      out[(rowbase + 4 * g + r) * 512 + col] =
          (x[ht][r] - mu) * rs * gamma[col] + beta[col];
    }
}

extern "C" void kernel_launch(void* const* d_in, const int* in_sizes, int n_in,
                              void* d_out, int out_size, void* d_ws, size_t ws_size,
                              hipStream_t stream) {
  const float* h     = (const float*)d_in[0];
  const float* rh    = (const float*)d_in[1];
  // d_in[2] = Wl, d_in[4] = al: dead (softmax shift-invariance along j)
  const float* Wr    = (const float*)d_in[3];
  const float* ar    = (const float*)d_in[5];
  const float* Wrs   = (const float*)d_in[6];
  const float* Wrt   = (const float*)d_in[7];
  const float* Wf    = (const float*)d_in[8];
  const float* gamma = (const float*)d_in[9];
  const float* beta  = (const float*)d_in[10];

  const size_t MB = 1ull << 20;
  char* ws = (char*)d_ws;
  unsigned short* frBt = (unsigned short*)(ws);                          // 4 MB
  unsigned short* rk   = (unsigned short*)(ws + 4 * MB);                 // 1 MB
  unsigned short* rq   = (unsigned short*)(ws + 5 * MB);                 // 1 MB
  float*          sr   = (float*)(ws + 6 * MB);                          // 128 KB
  float*          lbuf = (float*)(ws + 6 * MB + 256 * 1024);             // 512 KB
  unsigned short* WrT  = (unsigned short*)(ws + 6 * MB + 768 * 1024);    // 512 KB
  unsigned short* WfT  = (unsigned short*)(ws + 7 * MB + 256 * 1024);    // 512 KB
  unsigned short* O0   = (unsigned short*)(ws + 7 * MB + 768 * 1024);    // 4 MB
  unsigned short* O1   = (unsigned short*)(ws + 11 * MB + 768 * 1024);   // 4 MB (15.75 MB)
  unsigned short* O2   = (unsigned short*)d_out;                         // 4 MB (scratch)
  unsigned short* O3   = (unsigned short*)((char*)d_out + 4 * MB);       // 4 MB (scratch)

  hipLaunchKernelGGL(k_prep, dim3(2560), dim3(256), 0, stream,
                     Wr, Wf, rh, Wrs, Wrt, WrT, WfT, rk, rq);
  hipLaunchKernelGGL(k_proj_fr, dim3(256, 2), dim3(256), 0, stream, h, WrT, ar, frBt, sr);
  hipLaunchKernelGGL(k_attn, dim3(8, 16, 4), dim3(512), 0, stream, rk, rq, sr, frBt,
                     O0, O1, O2, O3, lbuf);
  hipLaunchKernelGGL(k_final, dim3(256), dim3(512), 0, stream, O0, O1, O2, O3, lbuf,
                     WfT, h, gamma, beta, (float*)d_out);
}